// Round 1
// baseline (1236.859 us; speedup 1.0000x reference)
//
#include <hip/hip_runtime.h>
#include <hip/hip_bf16.h>
#include <math.h>

typedef _Float16 f16;
typedef __attribute__((ext_vector_type(8))) _Float16 f16x8;
typedef __attribute__((ext_vector_type(4))) float f32x4;

#define MFMA16(A, B, C) __builtin_amdgcn_mfma_f32_16x16x32_f16(A, B, C, 0, 0, 0)

namespace {
constexpr int kB = 2048, kDout = 512;
constexpr int kNch = 16, kChunk = 3125, kNit = 49;  // 50000 = 16*3125, 3125 = 48*64+53
// workspace layout (bytes)
constexpr size_t WS_PROJ = 0;                                   // [2048][512] f32
constexpr size_t WS_QHI  = 4u * 1024 * 1024;                    // [2048][512] f16
constexpr size_t WS_QLO  = WS_QHI + 2u * 1024 * 1024;           // [2048][512] f16
constexpr size_t WS_M    = WS_QLO + 2u * 1024 * 1024;           // [16][2048] f32
constexpr size_t WS_L    = WS_M + (size_t)kNch * kB * 4;        // [16][2048] f32
constexpr size_t WS_PV   = WS_L + (size_t)kNch * kB * 4;        // [16][2048][512] f32
}

// ---------------------------------------------------------------------------
// Kernel 1: proj = x @ W^T + b   (f16 x3-split MFMA, near-fp32 accuracy)
// Also emits q_hi / q_lo f16 split of proj for the attention kernel.
// Grid (32, 8) of 64x64 tiles, 256 threads (4 waves, 2x2 of 32x32).
// ---------------------------------------------------------------------------
__global__ __launch_bounds__(256) void gemm1_kernel(
    const float* __restrict__ x, const float* __restrict__ W,
    const float* __restrict__ bias, float* __restrict__ proj,
    f16* __restrict__ qhi, f16* __restrict__ qlo)
{
  __shared__ f16 xh[2][64][40], xl[2][64][40], wh[2][64][40], wl[2][64][40];
  const int t = threadIdx.x;
  const int lane = t & 63, w = t >> 6;
  const int wr = w >> 1, wc = w & 1;
  const int g = lane >> 4, j = lane & 15;
  const int m0 = blockIdx.x * 64, n0 = blockIdx.y * 64;
  const int srow = t >> 2;            // 0..63
  const int soff = (t & 3) * 8;       // 0,8,16,24

  const f32x4 fzero = {0.f, 0.f, 0.f, 0.f};
  f32x4 acc[2][2], acc2[2][2];
  #pragma unroll
  for (int a = 0; a < 2; a++)
    #pragma unroll
    for (int bb = 0; bb < 2; bb++) { acc[a][bb] = fzero; acc2[a][bb] = fzero; }

  auto stage = [&](int k0s, int buf) {
    const float* xs  = x + (size_t)(m0 + srow) * 1024 + k0s + soff;
    const float* wsr = W + (size_t)(n0 + srow) * 1024 + k0s + soff;
    f16x8 hx, lx, hw, lw;
    #pragma unroll
    for (int i = 0; i < 8; i++) {
      float v = xs[i];
      f16 h = (f16)v;
      hx[i] = h;
      lx[i] = (f16)((v - (float)h) * 2048.0f);   // scaled lo (avoid f16 denorm flush)
      float u = wsr[i];
      f16 hu = (f16)u;
      hw[i] = hu;
      lw[i] = (f16)((u - (float)hu) * 2048.0f);
    }
    *(f16x8*)&xh[buf][srow][soff] = hx;
    *(f16x8*)&xl[buf][srow][soff] = lx;
    *(f16x8*)&wh[buf][srow][soff] = hw;
    *(f16x8*)&wl[buf][srow][soff] = lw;
  };

  stage(0, 0);
  for (int ks = 0; ks < 32; ks++) {
    __syncthreads();
    if (ks < 31) stage((ks + 1) * 32, (ks + 1) & 1);
    const int buf = ks & 1;
    f16x8 ah[2], al[2], bh[2], bl[2];
    #pragma unroll
    for (int mf = 0; mf < 2; mf++) {
      const int r = wr * 32 + mf * 16 + j;
      ah[mf] = *(const f16x8*)&xh[buf][r][g * 8];
      al[mf] = *(const f16x8*)&xl[buf][r][g * 8];
      const int c = wc * 32 + mf * 16 + j;
      bh[mf] = *(const f16x8*)&wh[buf][c][g * 8];
      bl[mf] = *(const f16x8*)&wl[buf][c][g * 8];
    }
    #pragma unroll
    for (int mf = 0; mf < 2; mf++)
      #pragma unroll
      for (int nf = 0; nf < 2; nf++) {
        acc[mf][nf]  = MFMA16(ah[mf], bh[nf], acc[mf][nf]);   // hi*hi
        acc2[mf][nf] = MFMA16(ah[mf], bl[nf], acc2[mf][nf]);  // hi*lo (x2^11)
        acc2[mf][nf] = MFMA16(al[mf], bh[nf], acc2[mf][nf]);  // lo*hi (x2^11)
      }
  }

  #pragma unroll
  for (int mf = 0; mf < 2; mf++)
    #pragma unroll
    for (int nf = 0; nf < 2; nf++)
      #pragma unroll
      for (int r = 0; r < 4; r++) {
        const int m = m0 + wr * 32 + mf * 16 + g * 4 + r;
        const int n = n0 + wc * 32 + nf * 16 + j;
        float p = acc[mf][nf][r] + acc2[mf][nf][r] * (1.0f / 2048.0f) + bias[n];
        proj[(size_t)m * 512 + n] = p;
        f16 h = (f16)p;
        qhi[(size_t)m * 512 + n] = h;
        qlo[(size_t)m * 512 + n] = (f16)(p - (float)h);
      }
}

// ---------------------------------------------------------------------------
// Kernel 2: flash-style partial attention over one (Q-tile=128 rows, chunk=3125
// keys). QK^T = (q_hi + q_lo)*k_f16 (x2-split), online softmax in registers,
// PV in f16. Writes per-chunk m, l, and un-normalized PV partial to ws.
// 8 waves x 16 rows; O acc 32x f32x4 = 128 VGPR; q_lo 16x f16x8 = 64 VGPR.
// LDS: q_hi [128][512] swizzled (131072) | K dbuf [2][64][72] == P [128][72]
// (18432) | Vt dbuf [2][32][72] (9216)  => 158720 B dynamic.
// ---------------------------------------------------------------------------
__global__ __launch_bounds__(512, 2) void attn_kernel(
    const float* __restrict__ Kf, const float* __restrict__ Vf,
    const f16* __restrict__ qhi_ws, const f16* __restrict__ qlo_ws,
    const float* __restrict__ beta_p,
    float* __restrict__ m_part, float* __restrict__ l_part,
    float* __restrict__ pv_part)
{
  extern __shared__ char smem[];
  char* const qh_b = smem;            // 131072
  char* const r1_b = smem + 131072;   // 18432 (K slabs / P)
  char* const vt_b = smem + 149504;   // 9216  (V^T slabs)

  const int t = threadIdx.x;
  const int lane = t & 63;
  const int w = t >> 6;
  const int g = lane >> 4;
  const int j = lane & 15;

  const int bid = blockIdx.x;
  const int ch = bid & 15;            // same-chunk blocks land on same XCD
  const int qt = bid >> 4;
  const int q0 = qt * 128;
  const int kbeg = ch * kChunk;
  const float beta = beta_p[0];

  // ---- stage q_hi -> LDS, XOR-swizzled 16B chunks (wave stages its own rows)
  {
    const int row = t >> 2;
    const f16* src = qhi_ws + (size_t)(q0 + row) * 512;
    const int swz = (row & 7) << 4;
    #pragma unroll
    for (int i = 0; i < 16; i++) {
      const int cc = (t & 3) + i * 4;   // 16B-chunk index 0..63
      f16x8 v = *(const f16x8*)(src + cc * 8);
      *(f16x8*)(qh_b + row * 1024 + ((cc * 16) ^ swz)) = v;
    }
  }
  // ---- q_lo -> registers, already in A-frag layout (row = 16w+j, k = 32i+8g+j')
  f16x8 qlo[16];
  {
    const f16* src = qlo_ws + (size_t)(q0 + w * 16 + j) * 512 + g * 8;
    #pragma unroll
    for (int i = 0; i < 16; i++) qlo[i] = *(const f16x8*)(src + i * 32);
  }

  const f32x4 fzero = {0.f, 0.f, 0.f, 0.f};
  f32x4 O[32];
  #pragma unroll
  for (int nf = 0; nf < 32; nf++) O[nf] = fzero;
  float mrow[4] = {-INFINITY, -INFINITY, -INFINITY, -INFINITY};
  float lrow[4] = {0.f, 0.f, 0.f, 0.f};

  const int skey   = t >> 3;          // staging key 0..63
  const int sdoff  = (t & 7) * 8;     // K stage d-offset
  const int svcoff = (t & 7) * 4;     // V stage col-offset
  const int ahrow  = w * 16 + j;
  const int aswz   = (j & 7) << 4;

  __syncthreads();

  for (int it = 0; it < kNit; it++) {
    const int kbase = it * 64;
    const bool kvalid = (kbase + skey) < kChunk;
    const float* Krow = Kf + (size_t)(kbeg + kbase + skey) * 512;
    const float* Vrow = Vf + (size_t)(kbeg + kbase + skey) * 512;

    float4 ka, kb;
    auto LOADK = [&](int s) {
      if (kvalid) {
        ka = *(const float4*)(Krow + s * 64 + sdoff);
        kb = *(const float4*)(Krow + s * 64 + sdoff + 4);
      } else {
        ka = make_float4(0.f, 0.f, 0.f, 0.f); kb = ka;
      }
    };
    auto WRITEK = [&](int s) {
      f16x8 h;
      h[0] = (f16)ka.x; h[1] = (f16)ka.y; h[2] = (f16)ka.z; h[3] = (f16)ka.w;
      h[4] = (f16)kb.x; h[5] = (f16)kb.y; h[6] = (f16)kb.z; h[7] = (f16)kb.w;
      *(f16x8*)(r1_b + (s & 1) * 9216 + skey * 144 + sdoff * 2) = h;
    };

    // ---------------- QK^T over 8 d-slabs of 64 ----------------
    LOADK(0); WRITEK(0);
    __syncthreads();

    f32x4 S[4];
    #pragma unroll
    for (int f = 0; f < 4; f++) S[f] = fzero;

    #pragma unroll
    for (int s = 0; s < 8; s++) {
      if (s < 7) LOADK(s + 1);                     // issue early (T14)
      #pragma unroll
      for (int sub = 0; sub < 2; sub++) {
        const int i = s * 2 + sub;
        f16x8 ahi = *(const f16x8*)(qh_b + ahrow * 1024 + ((i * 64 + g * 16) ^ aswz));
        #pragma unroll
        for (int f = 0; f < 4; f++) {
          f16x8 bk = *(const f16x8*)(r1_b + (s & 1) * 9216 + (f * 16 + j) * 144 + sub * 64 + g * 16);
          S[f] = MFMA16(ahi, bk, S[f]);
          S[f] = MFMA16(qlo[i], bk, S[f]);
        }
      }
      if (s < 7) WRITEK(s + 1);                    // write late
      __syncthreads();
    }

    // ---------------- online softmax (in registers; rows = 16w + 4g + r) ----
    float P[4][4];
    #pragma unroll
    for (int f = 0; f < 4; f++)
      #pragma unroll
      for (int r = 0; r < 4; r++) P[f][r] = beta * S[f][r];
    if (it == kNit - 1) {
      #pragma unroll
      for (int f = 0; f < 4; f++) {
        if (kbase + f * 16 + j >= kChunk) {
          #pragma unroll
          for (int r = 0; r < 4; r++) P[f][r] = -INFINITY;
        }
      }
    }
    float fac[4];
    #pragma unroll
    for (int r = 0; r < 4; r++) {
      float rm = fmaxf(fmaxf(P[0][r], P[1][r]), fmaxf(P[2][r], P[3][r]));
      rm = fmaxf(rm, __shfl_xor(rm, 1));
      rm = fmaxf(rm, __shfl_xor(rm, 2));
      rm = fmaxf(rm, __shfl_xor(rm, 4));
      rm = fmaxf(rm, __shfl_xor(rm, 8));
      const float mn = fmaxf(mrow[r], rm);
      fac[r] = __expf(mrow[r] - mn);
      mrow[r] = mn;
      float rs = 0.f;
      #pragma unroll
      for (int f = 0; f < 4; f++) { P[f][r] = __expf(P[f][r] - mn); rs += P[f][r]; }
      rs += __shfl_xor(rs, 1);
      rs += __shfl_xor(rs, 2);
      rs += __shfl_xor(rs, 4);
      rs += __shfl_xor(rs, 8);
      lrow[r] = lrow[r] * fac[r] + rs;
    }

    __syncthreads();   // (A) all K-slab reads done; r1 region becomes P

    float4 va;
    auto LOADV = [&](int cs) {
      if (kvalid) va = *(const float4*)(Vrow + cs * 32 + svcoff);
      else va = make_float4(0.f, 0.f, 0.f, 0.f);
    };
    auto WRITEV = [&](int cs) {   // transposed: Vt[col][key]
      char* base = vt_b + (cs & 1) * 4608 + skey * 2;
      *(f16*)(base + (svcoff + 0) * 144) = (f16)va.x;
      *(f16*)(base + (svcoff + 1) * 144) = (f16)va.y;
      *(f16*)(base + (svcoff + 2) * 144) = (f16)va.z;
      *(f16*)(base + (svcoff + 3) * 144) = (f16)va.w;
    };

    LOADV(0);
    {  // P -> LDS f16 (C-frag layout), wave-local rows
      char* pb = r1_b + (w * 16 + g * 4) * 144 + j * 2;
      #pragma unroll
      for (int f = 0; f < 4; f++)
        #pragma unroll
        for (int r = 0; r < 4; r++)
          *(f16*)(pb + r * 144 + f * 32) = (f16)P[f][r];
    }
    #pragma unroll
    for (int nf = 0; nf < 32; nf++) {   // rescale O (row mapping matches S)
      #pragma unroll
      for (int r = 0; r < 4; r++) O[nf][r] *= fac[r];
    }
    WRITEV(0);
    __syncthreads();   // (B) P + Vt(0) visible

    f16x8 PA0 = *(const f16x8*)(r1_b + ahrow * 144 + g * 16);
    f16x8 PA1 = *(const f16x8*)(r1_b + ahrow * 144 + 64 + g * 16);

    // ---------------- PV over 16 col-slabs of 32 ----------------
    #pragma unroll
    for (int cs = 0; cs < 16; cs++) {
      if (cs < 15) LOADV(cs + 1);
      #pragma unroll
      for (int nfl = 0; nfl < 2; nfl++) {
        const char* vb = vt_b + (cs & 1) * 4608 + (nfl * 16 + j) * 144 + g * 16;
        f16x8 B0 = *(const f16x8*)(vb);
        f16x8 B1 = *(const f16x8*)(vb + 64);
        O[cs * 2 + nfl] = MFMA16(PA0, B0, O[cs * 2 + nfl]);
        O[cs * 2 + nfl] = MFMA16(PA1, B1, O[cs * 2 + nfl]);
      }
      if (cs < 15) WRITEV(cs + 1);
      __syncthreads();
    }
  }

  // ---------------- write partials ----------------
  const size_t pvb = ((size_t)ch * kB + q0) * 512;
  #pragma unroll
  for (int nf = 0; nf < 32; nf++) {
    #pragma unroll
    for (int r = 0; r < 4; r++) {
      const int m = w * 16 + g * 4 + r;
      pv_part[pvb + (size_t)m * 512 + nf * 16 + j] = O[nf][r];
    }
  }
  if (j == 0) {
    #pragma unroll
    for (int r = 0; r < 4; r++) {
      const int m = w * 16 + g * 4 + r;
      m_part[ch * kB + q0 + m] = mrow[r];
      l_part[ch * kB + q0 + m] = lrow[r];
    }
  }
}

// ---------------------------------------------------------------------------
// Kernel 3: combine partials:  out = proj + alpha * (sum_c g_c pv_c)/(sum_c g_c l_c)
// ---------------------------------------------------------------------------
__global__ __launch_bounds__(256) void combine_kernel(
    const float* __restrict__ proj, const float* __restrict__ m_part,
    const float* __restrict__ l_part, const float* __restrict__ pv_part,
    const float* __restrict__ alpha_p, float* __restrict__ out)
{
  const int row = blockIdx.x;
  const int t = threadIdx.x;
  const float alpha = alpha_p[0];
  float M = -INFINITY;
  #pragma unroll
  for (int c = 0; c < kNch; c++) M = fmaxf(M, m_part[c * kB + row]);
  float gam[kNch];
  float T = 0.f;
  #pragma unroll
  for (int c = 0; c < kNch; c++) {
    gam[c] = __expf(m_part[c * kB + row] - M);
    T += gam[c] * l_part[c * kB + row];
  }
  const float s = alpha / T;
  #pragma unroll
  for (int half = 0; half < 2; half++) {
    const int col = t + half * 256;
    float acc = 0.f;
    #pragma unroll
    for (int c = 0; c < kNch; c++)
      acc += gam[c] * pv_part[((size_t)c * kB + row) * 512 + col];
    out[(size_t)row * 512 + col] = proj[(size_t)row * 512 + col] + acc * s;
  }
}

// ---------------------------------------------------------------------------
extern "C" void kernel_launch(void* const* d_in, const int* in_sizes, int n_in,
                              void* d_out, int out_size, void* d_ws, size_t ws_size,
                              hipStream_t stream) {
  (void)in_sizes; (void)n_in; (void)out_size; (void)ws_size;
  const float* x     = (const float*)d_in[0];
  const float* W     = (const float*)d_in[1];
  const float* bias  = (const float*)d_in[2];
  const float* cimg  = (const float*)d_in[3];
  const float* ctxt  = (const float*)d_in[4];
  const float* beta  = (const float*)d_in[5];
  const float* alpha = (const float*)d_in[6];
  float* out = (float*)d_out;
  char* ws = (char*)d_ws;

  float* proj = (float*)(ws + WS_PROJ);
  f16*   qhi  = (f16*)(ws + WS_QHI);
  f16*   qlo  = (f16*)(ws + WS_QLO);
  float* mp   = (float*)(ws + WS_M);
  float* lp   = (float*)(ws + WS_L);
  float* pv   = (float*)(ws + WS_PV);

  hipFuncSetAttribute((const void*)attn_kernel,
                      hipFuncAttributeMaxDynamicSharedMemorySize, 158720);

  gemm1_kernel<<<dim3(32, 8), 256, 0, stream>>>(x, W, bias, proj, qhi, qlo);
  attn_kernel<<<256, 512, 158720, stream>>>(cimg, ctxt, qhi, qlo, beta, mp, lp, pv);
  combine_kernel<<<2048, 256, 0, stream>>>(proj, mp, lp, pv, alpha, out);
}

// Round 2
// 496.179 us; speedup vs baseline: 2.4928x; 2.4928x over previous
//
#include <hip/hip_runtime.h>
#include <hip/hip_bf16.h>
#include <math.h>

typedef _Float16 f16;
typedef __attribute__((ext_vector_type(8))) _Float16 f16x8;
typedef __attribute__((ext_vector_type(4))) float f32x4;

#define MFMA16(A, B, C) __builtin_amdgcn_mfma_f32_16x16x32_f16(A, B, C, 0, 0, 0)
#define AS1 __attribute__((address_space(1)))
#define AS3 __attribute__((address_space(3)))

__device__ __forceinline__ void gld16(const char* g, char* l) {
  __builtin_amdgcn_global_load_lds((const AS1 void*)g, (AS3 void*)l, 16, 0, 0);
}

namespace {
constexpr int kB = 2048;
constexpr int kNch = 16, kChunk = 3125, kNit = 49;   // 50000 = 16*3125; 49*64 = 3136
constexpr int kKRows = 50112;                        // padded K16 rows (>= 46875+3136+64)
constexpr int kVStride = 3200;                       // padded keys per chunk in Vt16
// workspace layout (bytes)
constexpr size_t WS_PROJ = 0;                                   // [2048][512] f32
constexpr size_t WS_QHI  = WS_PROJ + (size_t)2048 * 512 * 4;    // [2048][512] f16
constexpr size_t WS_M    = WS_QHI + (size_t)2048 * 512 * 2;     // [16][2048] f32
constexpr size_t WS_L    = WS_M + (size_t)kNch * kB * 4;        // [16][2048] f32
constexpr size_t WS_PV   = WS_L + (size_t)kNch * kB * 4;        // [16][2048][512] f16 (normalized)
constexpr size_t WS_K16  = WS_PV + (size_t)kNch * kB * 512 * 2; // [50112][512] f16
constexpr size_t WS_VT   = WS_K16 + (size_t)kKRows * 512 * 2;   // [16][512][3200] f16
// LDS layout (attn)
constexpr int LDS_K  = 0;        // 64 rows x 1040 B (1024 data + 16 pad)  = 66560
constexpr int LDS_V  = 66560;    // 512 cols x 128 B (XOR-swizzled)        = 65536
constexpr int LDS_P  = 132096;   // 128 rows x 144 B                       = 18432
constexpr int LDS_SZ = 150528;
}

// ---------------------------------------------------------------------------
// K16: f16 copy of cache_image_features, rows >= 50000 zero-filled.
// ---------------------------------------------------------------------------
__global__ __launch_bounds__(256) void convk_kernel(const float* __restrict__ src,
                                                    f16* __restrict__ dst) {
  const size_t e = ((size_t)blockIdx.x * 256 + threadIdx.x) * 8;
  const int row = (int)(e >> 9);
  float4 a = make_float4(0.f, 0.f, 0.f, 0.f), b = a;
  if (row < 50000) {
    a = *(const float4*)(src + e);
    b = *(const float4*)(src + e + 4);
  }
  f16x8 h;
  h[0] = (f16)a.x; h[1] = (f16)a.y; h[2] = (f16)a.z; h[3] = (f16)a.w;
  h[4] = (f16)b.x; h[5] = (f16)b.y; h[6] = (f16)b.z; h[7] = (f16)b.w;
  *(f16x8*)(dst + e) = h;
}

// ---------------------------------------------------------------------------
// Vt16[ch][col][key] f16 transpose of cache_text_features; pad keys zeroed.
// grid (50, 8, 16), 256 threads, LDS-tiled 64x64.
// ---------------------------------------------------------------------------
__global__ __launch_bounds__(256) void transv_kernel(const float* __restrict__ Vf,
                                                     f16* __restrict__ Vt) {
  __shared__ float tile[64][65];
  const int kt = blockIdx.x, colt = blockIdx.y, ch = blockIdx.z;
  const int t = threadIdx.x;
  const int kbase = kt * 64, col0 = colt * 64;
  {
    const int key = t >> 2, cseg = (t & 3) * 16;
    const int kk = kbase + key;
    float4 v0 = make_float4(0.f, 0.f, 0.f, 0.f), v1 = v0, v2 = v0, v3 = v0;
    if (kk < kChunk) {
      const float* s = Vf + (size_t)(ch * kChunk + kk) * 512 + col0 + cseg;
      v0 = *(const float4*)(s);
      v1 = *(const float4*)(s + 4);
      v2 = *(const float4*)(s + 8);
      v3 = *(const float4*)(s + 12);
    }
    float* tr = &tile[key][cseg];
    tr[0] = v0.x;  tr[1] = v0.y;  tr[2] = v0.z;  tr[3] = v0.w;
    tr[4] = v1.x;  tr[5] = v1.y;  tr[6] = v1.z;  tr[7] = v1.w;
    tr[8] = v2.x;  tr[9] = v2.y;  tr[10] = v2.z; tr[11] = v2.w;
    tr[12] = v3.x; tr[13] = v3.y; tr[14] = v3.z; tr[15] = v3.w;
  }
  __syncthreads();
  {
    const int col = t >> 2, kw = (t & 3) * 16;
    f16x8 h0, h1;
    #pragma unroll
    for (int u = 0; u < 8; u++) h0[u] = (f16)tile[kw + u][col];
    #pragma unroll
    for (int u = 0; u < 8; u++) h1[u] = (f16)tile[kw + 8 + u][col];
    f16* d = Vt + ((size_t)ch * 512 + col0 + col) * kVStride + kbase + kw;
    *(f16x8*)(d) = h0;
    *(f16x8*)(d + 8) = h1;
  }
}

// ---------------------------------------------------------------------------
// Kernel 1: proj = x @ W^T + b   (f16 x3-split MFMA, near-fp32 accuracy)
// Also emits q_hi f16 of proj for the attention kernel.
// ---------------------------------------------------------------------------
__global__ __launch_bounds__(256) void gemm1_kernel(
    const float* __restrict__ x, const float* __restrict__ W,
    const float* __restrict__ bias, float* __restrict__ proj,
    f16* __restrict__ qhi)
{
  __shared__ f16 xh[2][64][40], xl[2][64][40], wh[2][64][40], wl[2][64][40];
  const int t = threadIdx.x;
  const int lane = t & 63, w = t >> 6;
  const int wr = w >> 1, wc = w & 1;
  const int g = lane >> 4, j = lane & 15;
  const int m0 = blockIdx.x * 64, n0 = blockIdx.y * 64;
  const int srow = t >> 2;
  const int soff = (t & 3) * 8;

  const f32x4 fzero = {0.f, 0.f, 0.f, 0.f};
  f32x4 acc[2][2], acc2[2][2];
  #pragma unroll
  for (int a = 0; a < 2; a++)
    #pragma unroll
    for (int bb = 0; bb < 2; bb++) { acc[a][bb] = fzero; acc2[a][bb] = fzero; }

  auto stage = [&](int k0s, int buf) {
    const float* xs  = x + (size_t)(m0 + srow) * 1024 + k0s + soff;
    const float* wsr = W + (size_t)(n0 + srow) * 1024 + k0s + soff;
    f16x8 hx, lx, hw, lw;
    #pragma unroll
    for (int i = 0; i < 8; i++) {
      float v = xs[i];
      f16 h = (f16)v;
      hx[i] = h;
      lx[i] = (f16)((v - (float)h) * 2048.0f);
      float u = wsr[i];
      f16 hu = (f16)u;
      hw[i] = hu;
      lw[i] = (f16)((u - (float)hu) * 2048.0f);
    }
    *(f16x8*)&xh[buf][srow][soff] = hx;
    *(f16x8*)&xl[buf][srow][soff] = lx;
    *(f16x8*)&wh[buf][srow][soff] = hw;
    *(f16x8*)&wl[buf][srow][soff] = lw;
  };

  stage(0, 0);
  for (int ks = 0; ks < 32; ks++) {
    __syncthreads();
    if (ks < 31) stage((ks + 1) * 32, (ks + 1) & 1);
    const int buf = ks & 1;
    f16x8 ah[2], al[2], bh[2], bl[2];
    #pragma unroll
    for (int mf = 0; mf < 2; mf++) {
      const int r = wr * 32 + mf * 16 + j;
      ah[mf] = *(const f16x8*)&xh[buf][r][g * 8];
      al[mf] = *(const f16x8*)&xl[buf][r][g * 8];
      const int c = wc * 32 + mf * 16 + j;
      bh[mf] = *(const f16x8*)&wh[buf][c][g * 8];
      bl[mf] = *(const f16x8*)&wl[buf][c][g * 8];
    }
    #pragma unroll
    for (int mf = 0; mf < 2; mf++)
      #pragma unroll
      for (int nf = 0; nf < 2; nf++) {
        acc[mf][nf]  = MFMA16(ah[mf], bh[nf], acc[mf][nf]);
        acc2[mf][nf] = MFMA16(ah[mf], bl[nf], acc2[mf][nf]);
        acc2[mf][nf] = MFMA16(al[mf], bh[nf], acc2[mf][nf]);
      }
  }

  #pragma unroll
  for (int mf = 0; mf < 2; mf++)
    #pragma unroll
    for (int nf = 0; nf < 2; nf++)
      #pragma unroll
      for (int r = 0; r < 4; r++) {
        const int m = m0 + wr * 32 + mf * 16 + g * 4 + r;
        const int n = n0 + wc * 32 + nf * 16 + j;
        float p = acc[mf][nf][r] + acc2[mf][nf][r] * (1.0f / 2048.0f) + bias[n];
        proj[(size_t)m * 512 + n] = p;
        qhi[(size_t)m * 512 + n] = (f16)p;
      }
}

// ---------------------------------------------------------------------------
// Kernel 2: flash attention partial, big-slab staging via global_load_lds.
// 256 blocks (16 Qtiles x 16 chunks), 512 threads, 4 barriers/iter, counted
// vmcnt(8). K LDS: 1040B row stride (pad, conflict-free). Vt LDS: 3-bit XOR
// swizzle matched by pre-swizzled global source.
// ---------------------------------------------------------------------------
__global__ __launch_bounds__(512, 2) void attn_kernel(
    const f16* __restrict__ K16, const f16* __restrict__ Vt16,
    const f16* __restrict__ qhi_ws, const float* __restrict__ beta_p,
    float* __restrict__ m_part, float* __restrict__ l_part,
    f16* __restrict__ pvn)
{
  extern __shared__ char smem[];
  char* const Kreg = smem + LDS_K;
  char* const Vreg = smem + LDS_V;
  char* const Preg = smem + LDS_P;

  const int t = threadIdx.x, lane = t & 63, w = t >> 6;
  const int g = lane >> 4, j = lane & 15;
  const int ch = blockIdx.x & 15, qt = blockIdx.x >> 4;
  const int q0 = qt * 128;
  const float beta = beta_p[0];

  // ---- q_hi -> registers (A-frag layout: row = 16w+j, k = 32i + 8g + ...)
  f16x8 qh[16];
  {
    const f16* qsrc = qhi_ws + (size_t)(q0 + w * 16 + j) * 512 + g * 8;
    #pragma unroll
    for (int i = 0; i < 16; i++) qh[i] = *(const f16x8*)(qsrc + i * 32);
  }
  __builtin_amdgcn_sched_barrier(0);   // keep qh loads before stage issues

  const char* const Kg = (const char*)K16 + (size_t)(ch * kChunk) * 1024;
  const char* const Vg = (const char*)Vt16 + (size_t)ch * 512 * kVStride * 2;
  const int vlo = ((lane & 7) ^ (lane >> 3)) * 16;   // pre-swizzled V source off

  auto stageK = [&](int kbase) {
    const char* base = Kg + (size_t)kbase * 1024;
    #pragma unroll
    for (int u = 0; u < 8; u++)
      gld16(base + (w * 8 + u) * 1024 + lane * 16, Kreg + (w * 8 + u) * 1040);
  };
  auto stageV = [&](int kbase) {
    const char* base = Vg + (size_t)kbase * 2 + vlo;
    #pragma unroll
    for (int u = 0; u < 8; u++) {
      const int col = (w * 8 + u) * 8 + (lane >> 3);
      gld16(base + (size_t)col * (kVStride * 2), Vreg + (w * 8 + u) * 1024);
    }
  };

  // hoisted conflict-free read bases
  const char* const kb0 = Kreg + (16 * 0 + j) * 1040 + g * 16;
  const char* const kb1 = Kreg + (16 * 1 + j) * 1040 + g * 16;
  const char* const kb2 = Kreg + (16 * 2 + j) * 1040 + g * 16;
  const char* const kb3 = Kreg + (16 * 3 + j) * 1040 + g * 16;
  const int vswz = (j & 7) << 4;
  const char* const vb0 = Vreg + j * 128 + ((g * 16) ^ vswz);
  const char* const vb1 = Vreg + j * 128 + ((64 + g * 16) ^ vswz);
  const int ahrow = w * 16 + j;
  const char* const pa0 = Preg + ahrow * 144 + g * 16;

  const f32x4 fzero = {0.f, 0.f, 0.f, 0.f};
  f32x4 O[32];
  #pragma unroll
  for (int nf = 0; nf < 32; nf++) O[nf] = fzero;
  float mrow[4] = {-INFINITY, -INFINITY, -INFINITY, -INFINITY};
  float lrow[4] = {0.f, 0.f, 0.f, 0.f};

  // prologue: K0 + V0 in flight; wait K0 only
  stageK(0);
  stageV(0);
  asm volatile("s_waitcnt vmcnt(8)" ::: "memory");
  __builtin_amdgcn_s_barrier();

  for (int it = 0; it < kNit; it++) {
    // ---------------- QK^T (reads Kreg; V[it] loads in flight) ----------
    f32x4 S[4];
    #pragma unroll
    for (int f = 0; f < 4; f++) S[f] = fzero;
    __builtin_amdgcn_s_setprio(1);
    #pragma unroll
    for (int i = 0; i < 16; i++) {
      const f16x8 b0 = *(const f16x8*)(kb0 + i * 64);
      const f16x8 b1 = *(const f16x8*)(kb1 + i * 64);
      const f16x8 b2 = *(const f16x8*)(kb2 + i * 64);
      const f16x8 b3 = *(const f16x8*)(kb3 + i * 64);
      S[0] = MFMA16(qh[i], b0, S[0]);
      S[1] = MFMA16(qh[i], b1, S[1]);
      S[2] = MFMA16(qh[i], b2, S[2]);
      S[3] = MFMA16(qh[i], b3, S[3]);
    }
    __builtin_amdgcn_s_setprio(0);

    // ---------------- online softmax in registers ----------------------
    #pragma unroll
    for (int f = 0; f < 4; f++)
      #pragma unroll
      for (int r = 0; r < 4; r++) S[f][r] *= beta;
    if (it == kNit - 1) {
      #pragma unroll
      for (int f = 0; f < 4; f++)
        if (it * 64 + f * 16 + j >= kChunk) {
          #pragma unroll
          for (int r = 0; r < 4; r++) S[f][r] = -INFINITY;
        }
    }
    float fac[4];
    #pragma unroll
    for (int r = 0; r < 4; r++) {
      float rm = fmaxf(fmaxf(S[0][r], S[1][r]), fmaxf(S[2][r], S[3][r]));
      rm = fmaxf(rm, __shfl_xor(rm, 1));
      rm = fmaxf(rm, __shfl_xor(rm, 2));
      rm = fmaxf(rm, __shfl_xor(rm, 4));
      rm = fmaxf(rm, __shfl_xor(rm, 8));
      const float mn = fmaxf(mrow[r], rm);
      fac[r] = __expf(mrow[r] - mn);
      mrow[r] = mn;
      float rs = 0.f;
      #pragma unroll
      for (int f = 0; f < 4; f++) { S[f][r] = __expf(S[f][r] - mn); rs += S[f][r]; }
      rs += __shfl_xor(rs, 1);
      rs += __shfl_xor(rs, 2);
      rs += __shfl_xor(rs, 4);
      rs += __shfl_xor(rs, 8);
      lrow[r] = lrow[r] * fac[r] + rs;
    }

    asm volatile("" ::: "memory");
    __builtin_amdgcn_s_barrier();              // (1) all done reading Kreg

    stageK((it + 1) * 64);                     // K[it+1] flies under PV (padded)
    {  // P -> LDS (C-frag scatter), wave-local rows
      char* pb = Preg + (w * 16 + g * 4) * 144 + j * 2;
      #pragma unroll
      for (int f = 0; f < 4; f++)
        #pragma unroll
        for (int r = 0; r < 4; r++)
          *(f16*)(pb + r * 144 + f * 32) = (f16)S[f][r];
    }
    #pragma unroll
    for (int nf = 0; nf < 32; nf++)
      #pragma unroll
      for (int r = 0; r < 4; r++) O[nf][r] *= fac[r];

    asm volatile("s_waitcnt vmcnt(8) lgkmcnt(0)" ::: "memory");  // V[it] ready
    __builtin_amdgcn_s_barrier();              // (2) Vreg + Preg visible

    // ---------------- PV (reads Vreg, Preg; K[it+1] in flight) ----------
    const f16x8 PA0 = *(const f16x8*)(pa0);
    const f16x8 PA1 = *(const f16x8*)(pa0 + 64);
    __builtin_amdgcn_s_setprio(1);
    #pragma unroll
    for (int nf = 0; nf < 32; nf++) {
      const f16x8 B0 = *(const f16x8*)(vb0 + nf * 2048);
      const f16x8 B1 = *(const f16x8*)(vb1 + nf * 2048);
      O[nf] = MFMA16(PA0, B0, O[nf]);
      O[nf] = MFMA16(PA1, B1, O[nf]);
    }
    __builtin_amdgcn_s_setprio(0);

    asm volatile("" ::: "memory");
    __builtin_amdgcn_s_barrier();              // (3) all done reading Vreg

    stageV((it + 1) * 64);                     // V[it+1] flies under next QK
    asm volatile("s_waitcnt vmcnt(8)" ::: "memory");  // K[it+1] ready
    __builtin_amdgcn_s_barrier();              // (4)
  }

  // ---------------- epilogue: normalized pv + stats ----------------
  float inv[4];
  #pragma unroll
  for (int r = 0; r < 4; r++) inv[r] = 1.0f / lrow[r];
  const size_t pvb = ((size_t)ch * kB + q0) * 512;
  #pragma unroll
  for (int nf = 0; nf < 32; nf++)
    #pragma unroll
    for (int r = 0; r < 4; r++) {
      const int m = w * 16 + g * 4 + r;
      pvn[pvb + (size_t)m * 512 + nf * 16 + j] = (f16)(O[nf][r] * inv[r]);
    }
  if (j == 0) {
    #pragma unroll
    for (int r = 0; r < 4; r++) {
      const int m = w * 16 + g * 4 + r;
      m_part[ch * kB + q0 + m] = mrow[r];
      l_part[ch * kB + q0 + m] = lrow[r];
    }
  }
  asm volatile("s_waitcnt vmcnt(0)" ::: "memory");  // drain dangling stage DMA
}

// ---------------------------------------------------------------------------
// Kernel 3: combine:  out = proj + alpha * (sum_c g_c l_c pvn_c) / (sum_c g_c l_c)
// ---------------------------------------------------------------------------
__global__ __launch_bounds__(256) void combine_kernel(
    const float* __restrict__ proj, const float* __restrict__ m_part,
    const float* __restrict__ l_part, const f16* __restrict__ pvn,
    const float* __restrict__ alpha_p, float* __restrict__ out)
{
  const int row = blockIdx.x;
  const int t = threadIdx.x;
  const float alpha = alpha_p[0];
  float M = -INFINITY;
  #pragma unroll
  for (int c = 0; c < kNch; c++) M = fmaxf(M, m_part[c * kB + row]);
  float gl[kNch];
  float T = 0.f;
  #pragma unroll
  for (int c = 0; c < kNch; c++) {
    gl[c] = __expf(m_part[c * kB + row] - M) * l_part[c * kB + row];
    T += gl[c];
  }
  const float s = alpha / T;
  #pragma unroll
  for (int half = 0; half < 2; half++) {
    const int col = t + half * 256;
    float acc = 0.f;
    #pragma unroll
    for (int c = 0; c < kNch; c++)
      acc += gl[c] * (float)pvn[((size_t)c * kB + row) * 512 + col];
    out[(size_t)row * 512 + col] = proj[(size_t)row * 512 + col] + acc * s;
  }
}

// ---------------------------------------------------------------------------
extern "C" void kernel_launch(void* const* d_in, const int* in_sizes, int n_in,
                              void* d_out, int out_size, void* d_ws, size_t ws_size,
                              hipStream_t stream) {
  (void)in_sizes; (void)n_in; (void)out_size; (void)ws_size;
  const float* x     = (const float*)d_in[0];
  const float* W     = (const float*)d_in[1];
  const float* bias  = (const float*)d_in[2];
  const float* cimg  = (const float*)d_in[3];
  const float* ctxt  = (const float*)d_in[4];
  const float* beta  = (const float*)d_in[5];
  const float* alpha = (const float*)d_in[6];
  float* out = (float*)d_out;
  char* ws = (char*)d_ws;

  float* proj = (float*)(ws + WS_PROJ);
  f16*   qhi  = (f16*)(ws + WS_QHI);
  float* mp   = (float*)(ws + WS_M);
  float* lp   = (float*)(ws + WS_L);
  f16*   pvn  = (f16*)(ws + WS_PV);
  f16*   K16  = (f16*)(ws + WS_K16);
  f16*   Vt16 = (f16*)(ws + WS_VT);

  hipFuncSetAttribute((const void*)attn_kernel,
                      hipFuncAttributeMaxDynamicSharedMemorySize, LDS_SZ);

  convk_kernel<<<(kKRows * 512 / 8 + 255) / 256, 256, 0, stream>>>(cimg, K16);
  transv_kernel<<<dim3(kVStride / 64, 8, kNch), 256, 0, stream>>>(ctxt, Vt16);
  gemm1_kernel<<<dim3(32, 8), 256, 0, stream>>>(x, W, bias, proj, qhi);
  attn_kernel<<<256, 512, LDS_SZ, stream>>>(K16, Vt16, qhi, beta, mp, lp, pvn);
  combine_kernel<<<2048, 256, 0, stream>>>(proj, mp, lp, pvn, alpha, out);
}

// Round 3
// 408.808 us; speedup vs baseline: 3.0255x; 1.2137x over previous
//
#include <hip/hip_runtime.h>
#include <hip/hip_bf16.h>
#include <math.h>

typedef _Float16 f16;
typedef __attribute__((ext_vector_type(8))) _Float16 f16x8;
typedef __attribute__((ext_vector_type(4))) float f32x4;
typedef __attribute__((ext_vector_type(16))) float f32x16;
typedef __attribute__((ext_vector_type(4))) unsigned int u32x4;
typedef __attribute__((ext_vector_type(2))) unsigned int u32x2;

#define MFMA16(A, B, C) __builtin_amdgcn_mfma_f32_16x16x32_f16(A, B, C, 0, 0, 0)
#define MFMA32(A, B, C) __builtin_amdgcn_mfma_f32_32x32x16_f16(A, B, C, 0, 0, 0)
#define AS1 __attribute__((address_space(1)))
#define AS3 __attribute__((address_space(3)))

__device__ __forceinline__ void gld16(const char* g, char* l) {
  __builtin_amdgcn_global_load_lds((const AS1 void*)g, (AS3 void*)l, 16, 0, 0);
}

__device__ __forceinline__ unsigned pk2(float a, float b) {
  f16 x = (f16)a, y = (f16)b;
  unsigned short ux = __builtin_bit_cast(unsigned short, x);
  unsigned short uy = __builtin_bit_cast(unsigned short, y);
  return (unsigned)ux | ((unsigned)uy << 16);
}

namespace {
constexpr int kB = 2048;
constexpr int kNch = 16, kChunk = 3125, kNit = 98;   // 98*32 = 3136 >= 3125
constexpr int kKRows = 50176;                        // padded K16 rows
constexpr int kVStride = 3200;                       // padded keys per chunk in Vt16
// workspace layout (bytes)
constexpr size_t WS_PROJ = 0;                                   // [2048][512] f32
constexpr size_t WS_QHI  = WS_PROJ + (size_t)2048 * 512 * 4;    // [2048][512] f16
constexpr size_t WS_M    = WS_QHI + (size_t)2048 * 512 * 2;     // [16][2048] f32
constexpr size_t WS_L    = WS_M + (size_t)kNch * kB * 4;        // [16][2048] f32
constexpr size_t WS_PV   = WS_L + (size_t)kNch * kB * 4;        // [16][2048][512] f16 (normalized)
constexpr size_t WS_K16  = WS_PV + (size_t)kNch * kB * 512 * 2; // [50176][512] f16
constexpr size_t WS_VT   = WS_K16 + (size_t)kKRows * 512 * 2;   // [16][512][3200] f16
// attn LDS layout: Kbuf 2x(32x1040) | Vbuf 2x(512x64) | SxP 4x4096 | fac 512
constexpr int LDS_K0 = 0, LDS_K1 = 33280;
constexpr int LDS_V0 = 66560, LDS_V1 = 99328;
constexpr int LDS_SXP = 132096;
constexpr int LDS_FAC = 148480;
constexpr int LDS_SZ  = 148992;
}

// ---------------------------------------------------------------------------
// K16: f16 copy of cache_image_features, rows >= 50000 zero-filled.
// ---------------------------------------------------------------------------
__global__ __launch_bounds__(256) void convk_kernel(const float* __restrict__ src,
                                                    f16* __restrict__ dst) {
  const size_t e = ((size_t)blockIdx.x * 256 + threadIdx.x) * 8;
  const int row = (int)(e >> 9);
  float4 a = make_float4(0.f, 0.f, 0.f, 0.f), b = a;
  if (row < 50000) {
    a = *(const float4*)(src + e);
    b = *(const float4*)(src + e + 4);
  }
  f16x8 h;
  h[0] = (f16)a.x; h[1] = (f16)a.y; h[2] = (f16)a.z; h[3] = (f16)a.w;
  h[4] = (f16)b.x; h[5] = (f16)b.y; h[6] = (f16)b.z; h[7] = (f16)b.w;
  *(f16x8*)(dst + e) = h;
}

// ---------------------------------------------------------------------------
// Vt16[ch][col][key] f16 transpose of cache_text_features; pad keys zeroed.
// ---------------------------------------------------------------------------
__global__ __launch_bounds__(256) void transv_kernel(const float* __restrict__ Vf,
                                                     f16* __restrict__ Vt) {
  __shared__ float tile[64][65];
  const int kt = blockIdx.x, colt = blockIdx.y, ch = blockIdx.z;
  const int t = threadIdx.x;
  const int kbase = kt * 64, col0 = colt * 64;
  {
    const int key = t >> 2, cseg = (t & 3) * 16;
    const int kk = kbase + key;
    float4 v0 = make_float4(0.f, 0.f, 0.f, 0.f), v1 = v0, v2 = v0, v3 = v0;
    if (kk < kChunk) {
      const float* s = Vf + (size_t)(ch * kChunk + kk) * 512 + col0 + cseg;
      v0 = *(const float4*)(s);
      v1 = *(const float4*)(s + 4);
      v2 = *(const float4*)(s + 8);
      v3 = *(const float4*)(s + 12);
    }
    float* tr = &tile[key][cseg];
    tr[0] = v0.x;  tr[1] = v0.y;  tr[2] = v0.z;  tr[3] = v0.w;
    tr[4] = v1.x;  tr[5] = v1.y;  tr[6] = v1.z;  tr[7] = v1.w;
    tr[8] = v2.x;  tr[9] = v2.y;  tr[10] = v2.z; tr[11] = v2.w;
    tr[12] = v3.x; tr[13] = v3.y; tr[14] = v3.z; tr[15] = v3.w;
  }
  __syncthreads();
  {
    const int col = t >> 2, kw = (t & 3) * 16;
    f16x8 h0, h1;
    #pragma unroll
    for (int u = 0; u < 8; u++) h0[u] = (f16)tile[kw + u][col];
    #pragma unroll
    for (int u = 0; u < 8; u++) h1[u] = (f16)tile[kw + 8 + u][col];
    f16* d = Vt + ((size_t)ch * 512 + col0 + col) * kVStride + kbase + kw;
    *(f16x8*)(d) = h0;
    *(f16x8*)(d + 8) = h1;
  }
}

// ---------------------------------------------------------------------------
// Kernel 1: proj = x @ W^T + b   (f16 x3-split MFMA, near-fp32 accuracy)
// ---------------------------------------------------------------------------
__global__ __launch_bounds__(256) void gemm1_kernel(
    const float* __restrict__ x, const float* __restrict__ W,
    const float* __restrict__ bias, float* __restrict__ proj,
    f16* __restrict__ qhi)
{
  __shared__ f16 xh[2][64][40], xl[2][64][40], wh[2][64][40], wl[2][64][40];
  const int t = threadIdx.x;
  const int lane = t & 63, w = t >> 6;
  const int wr = w >> 1, wc = w & 1;
  const int g = lane >> 4, j = lane & 15;
  const int m0 = blockIdx.x * 64, n0 = blockIdx.y * 64;
  const int srow = t >> 2;
  const int soff = (t & 3) * 8;

  const f32x4 fzero = {0.f, 0.f, 0.f, 0.f};
  f32x4 acc[2][2], acc2[2][2];
  #pragma unroll
  for (int a = 0; a < 2; a++)
    #pragma unroll
    for (int bb = 0; bb < 2; bb++) { acc[a][bb] = fzero; acc2[a][bb] = fzero; }

  auto stage = [&](int k0s, int buf) {
    const float* xs  = x + (size_t)(m0 + srow) * 1024 + k0s + soff;
    const float* wsr = W + (size_t)(n0 + srow) * 1024 + k0s + soff;
    f16x8 hx, lx, hw, lw;
    #pragma unroll
    for (int i = 0; i < 8; i++) {
      float v = xs[i];
      f16 h = (f16)v;
      hx[i] = h;
      lx[i] = (f16)((v - (float)h) * 2048.0f);
      float u = wsr[i];
      f16 hu = (f16)u;
      hw[i] = hu;
      lw[i] = (f16)((u - (float)hu) * 2048.0f);
    }
    *(f16x8*)&xh[buf][srow][soff] = hx;
    *(f16x8*)&xl[buf][srow][soff] = lx;
    *(f16x8*)&wh[buf][srow][soff] = hw;
    *(f16x8*)&wl[buf][srow][soff] = lw;
  };

  stage(0, 0);
  for (int ks = 0; ks < 32; ks++) {
    __syncthreads();
    if (ks < 31) stage((ks + 1) * 32, (ks + 1) & 1);
    const int buf = ks & 1;
    f16x8 ah[2], al[2], bh[2], bl[2];
    #pragma unroll
    for (int mf = 0; mf < 2; mf++) {
      const int r = wr * 32 + mf * 16 + j;
      ah[mf] = *(const f16x8*)&xh[buf][r][g * 8];
      al[mf] = *(const f16x8*)&xl[buf][r][g * 8];
      const int c = wc * 32 + mf * 16 + j;
      bh[mf] = *(const f16x8*)&wh[buf][c][g * 8];
      bl[mf] = *(const f16x8*)&wl[buf][c][g * 8];
    }
    #pragma unroll
    for (int mf = 0; mf < 2; mf++)
      #pragma unroll
      for (int nf = 0; nf < 2; nf++) {
        acc[mf][nf]  = MFMA16(ah[mf], bh[nf], acc[mf][nf]);
        acc2[mf][nf] = MFMA16(ah[mf], bl[nf], acc2[mf][nf]);
        acc2[mf][nf] = MFMA16(al[mf], bh[nf], acc2[mf][nf]);
      }
  }

  #pragma unroll
  for (int mf = 0; mf < 2; mf++)
    #pragma unroll
    for (int nf = 0; nf < 2; nf++)
      #pragma unroll
      for (int r = 0; r < 4; r++) {
        const int m = m0 + wr * 32 + mf * 16 + g * 4 + r;
        const int n = n0 + wc * 32 + nf * 16 + j;
        float p = acc[mf][nf][r] + acc2[mf][nf][r] * (1.0f / 2048.0f) + bias[n];
        proj[(size_t)m * 512 + n] = p;
        qhi[(size_t)m * 512 + n] = (f16)p;
      }
}

// ---------------------------------------------------------------------------
// Kernel 2: flash attention partial, 32x32x16 MFMA, swapped QK^T (S^T),
// d-split QK / col-split PV across wave pairs, P in registers, 3 barriers/iter,
// double-buffered K/V slabs staged via global_load_lds.
// Waves: qb = w&3 (32 q-rows), dh = w>>2 (d-half for QK, col-half for PV).
// ---------------------------------------------------------------------------
__global__ __launch_bounds__(512, 2) void attn_kernel(
    const f16* __restrict__ K16, const f16* __restrict__ Vt16,
    const f16* __restrict__ qhi_ws, const float* __restrict__ beta_p,
    float* __restrict__ m_part, float* __restrict__ l_part,
    f16* __restrict__ pvn)
{
  extern __shared__ char smem[];
  const int t = threadIdx.x, lane = t & 63, w = t >> 6;
  const int c = lane & 31, h = lane >> 5;
  const int qb = w & 3, dh = w >> 2;
  const int ch = blockIdx.x & 15, qt = blockIdx.x >> 4;
  const int q0 = qt * 128;
  const float beta = beta_p[0];

  char* const Kb0 = smem + LDS_K0;
  char* const Kb1 = smem + LDS_K1;
  char* const Vb0 = smem + LDS_V0;
  char* const Vb1 = smem + LDS_V1;
  char* const SxP = smem + LDS_SXP + qb * 4096;
  float* const facl = (float*)(smem + LDS_FAC);

  // ---- Q -> registers as B-frags: lane holds q-col = qb*32+c, k-chunk h*8.
  // frag i covers d = dh*256 + i*16 + h*8 .. +7
  f16x8 Qf[16];
  {
    const f16* qsrc = qhi_ws + (size_t)(q0 + qb * 32 + c) * 512 + dh * 256 + h * 8;
    #pragma unroll
    for (int i = 0; i < 16; i++) Qf[i] = *(const f16x8*)(qsrc + i * 16);
  }

  const char* const Kg = (const char*)K16 + (size_t)(ch * kChunk) * 1024;
  const char* const Vg = (const char*)Vt16 + (size_t)ch * 512 * (kVStride * 2);
  const int vlo = (((lane & 3) ^ ((lane >> 2) & 3)) << 4);  // pre-swizzled V src

  auto stageK = [&](int it, char* dstbuf) {
    const char* src = Kg + (size_t)(it * 32 + w * 4) * 1024 + lane * 16;
    char* dst = dstbuf + (w * 4) * 1040 + lane * 16;
    #pragma unroll
    for (int u = 0; u < 4; u++) gld16(src + u * 1024, dst + u * 1040);
  };
  auto stageV = [&](int it, char* dstbuf) {
    const char* src = Vg + (size_t)(w * 64 + (lane >> 2)) * (kVStride * 2) + it * 64 + vlo;
    char* dst = dstbuf + (w * 64) * 64 + lane * 16;
    #pragma unroll
    for (int u = 0; u < 4; u++)
      gld16(src + (size_t)(u * 16) * (kVStride * 2), dst + u * 1024);
  };

  // LDS read offsets (bank-conflict-free patterns)
  const int kroff = c * 1040 + dh * 512 + h * 16;                       // QK A-frag
  const int vroff0 = (dh * 256 + c) * 64 + ((h * 16) ^ ((c & 3) << 4)); // PV ks=0
  const int vroff1 = (dh * 256 + c) * 64 + ((32 + h * 16) ^ ((c & 3) << 4)); // ks=1

  f32x16 O[8];
  #pragma unroll
  for (int nf = 0; nf < 8; nf++)
    #pragma unroll
    for (int r = 0; r < 16; r++) O[nf][r] = 0.f;
  float mrow = -INFINITY, lrow = 0.f;

  stageK(0, Kb0);
  stageV(0, Vb0);
  asm volatile("s_waitcnt vmcnt(0)" ::: "memory");
  __builtin_amdgcn_s_barrier();

  for (int it = 0; it < kNit; it++) {
    const int p = it & 1;
    char* const Kp = p ? Kb1 : Kb0;
    char* const Vp = p ? Vb1 : Vb0;
    if (it + 1 < kNit) {
      stageK(it + 1, p ? Kb0 : Kb1);
      stageV(it + 1, p ? Vb0 : Vb1);
    }

    // ---------------- QK: S^T = K . Q over this wave's d-half -------------
    f32x16 S;
    #pragma unroll
    for (int r = 0; r < 16; r++) S[r] = 0.f;
    const char* ka = Kp + kroff;
    __builtin_amdgcn_s_setprio(1);
    #pragma unroll
    for (int i = 0; i < 16; i++) {
      f16x8 a = *(const f16x8*)(ka + i * 32);
      S = MFMA32(a, Qf[i], S);
    }
    __builtin_amdgcn_s_setprio(0);

    if (dh == 1) {  // write d-partial (f32), lane-major layout, conflict-free
      f32x4 v0 = {S[0], S[1], S[2], S[3]};
      f32x4 v1 = {S[4], S[5], S[6], S[7]};
      f32x4 v2 = {S[8], S[9], S[10], S[11]};
      f32x4 v3 = {S[12], S[13], S[14], S[15]};
      *(f32x4*)(SxP + 0 * 1024 + lane * 16) = v0;
      *(f32x4*)(SxP + 1 * 1024 + lane * 16) = v1;
      *(f32x4*)(SxP + 2 * 1024 + lane * 16) = v2;
      *(f32x4*)(SxP + 3 * 1024 + lane * 16) = v3;
    }
    asm volatile("s_waitcnt lgkmcnt(0)" ::: "memory");
    __builtin_amdgcn_s_barrier();                           // (1)

    u32x4 B0, B1;
    float fc;
    if (dh == 0) {
      // combine partner d-half
      #pragma unroll
      for (int cc = 0; cc < 4; cc++) {
        f32x4 v = *(const f32x4*)(SxP + cc * 1024 + lane * 16);
        S[4 * cc + 0] += v.x; S[4 * cc + 1] += v.y;
        S[4 * cc + 2] += v.z; S[4 * cc + 3] += v.w;
      }
      #pragma unroll
      for (int r = 0; r < 16; r++) S[r] *= beta;
      if (it == kNit - 1) {
        #pragma unroll
        for (int r = 0; r < 16; r++) {
          const int key = it * 32 + (r & 3) + 8 * (r >> 2) + 4 * h;
          if (key >= kChunk) S[r] = -INFINITY;
        }
      }
      // online softmax: lane owns one q-row; 16 keys in-lane + 16 at lane^32
      float pm = S[0];
      #pragma unroll
      for (int r = 1; r < 16; r++) pm = fmaxf(pm, S[r]);
      pm = fmaxf(pm, __shfl_xor(pm, 32));
      const float mn = fmaxf(mrow, pm);
      fc = __expf(mrow - mn);
      mrow = mn;
      float pr[16], rs = 0.f;
      #pragma unroll
      for (int r = 0; r < 16; r++) { pr[r] = __expf(S[r] - mn); rs += pr[r]; }
      rs += __shfl_xor(rs, 32);
      lrow = lrow * fc + rs;
      // build PV B-frags in registers (pack + half-swap + select)
      unsigned pA0 = pk2(pr[0], pr[1]),  pA1 = pk2(pr[2], pr[3]);
      unsigned pB0 = pk2(pr[4], pr[5]),  pB1 = pk2(pr[6], pr[7]);
      unsigned pC0 = pk2(pr[8], pr[9]),  pC1 = pk2(pr[10], pr[11]);
      unsigned pD0 = pk2(pr[12], pr[13]), pD1 = pk2(pr[14], pr[15]);
      unsigned sA0 = __shfl_xor(pA0, 32), sA1 = __shfl_xor(pA1, 32);
      unsigned sB0 = __shfl_xor(pB0, 32), sB1 = __shfl_xor(pB1, 32);
      unsigned sC0 = __shfl_xor(pC0, 32), sC1 = __shfl_xor(pC1, 32);
      unsigned sD0 = __shfl_xor(pD0, 32), sD1 = __shfl_xor(pD1, 32);
      B0[0] = h ? sB0 : pA0;  B0[1] = h ? sB1 : pA1;
      B0[2] = h ? pB0 : sA0;  B0[3] = h ? pB1 : sA1;
      B1[0] = h ? sD0 : pC0;  B1[1] = h ? sD1 : pC1;
      B1[2] = h ? pD0 : sC0;  B1[3] = h ? pD1 : sC1;
      // hand off P + fac to partner
      *(u32x4*)(SxP + 0 * 1024 + lane * 16) = B0;
      *(u32x4*)(SxP + 1 * 1024 + lane * 16) = B1;
      if (h == 0) facl[qb * 32 + c] = fc;
      #pragma unroll
      for (int nf = 0; nf < 8; nf++)
        #pragma unroll
        for (int r = 0; r < 16; r++) O[nf][r] *= fc;
    }
    asm volatile("s_waitcnt lgkmcnt(0)" ::: "memory");
    __builtin_amdgcn_s_barrier();                           // (2)
    if (dh == 1) {
      B0 = *(const u32x4*)(SxP + 0 * 1024 + lane * 16);
      B1 = *(const u32x4*)(SxP + 1 * 1024 + lane * 16);
      fc = facl[qb * 32 + c];
      #pragma unroll
      for (int nf = 0; nf < 8; nf++)
        #pragma unroll
        for (int r = 0; r < 16; r++) O[nf][r] *= fc;
    }

    // ---------------- PV: O^T += V^T . P^T over this wave's col-half ------
    const f16x8 pb0 = __builtin_bit_cast(f16x8, B0);
    const f16x8 pb1 = __builtin_bit_cast(f16x8, B1);
    __builtin_amdgcn_s_setprio(1);
    #pragma unroll
    for (int cf = 0; cf < 8; cf++) {
      f16x8 a0 = *(const f16x8*)(Vp + vroff0 + cf * 2048);
      f16x8 a1 = *(const f16x8*)(Vp + vroff1 + cf * 2048);
      O[cf] = MFMA32(a0, pb0, O[cf]);
      O[cf] = MFMA32(a1, pb1, O[cf]);
    }
    __builtin_amdgcn_s_setprio(0);

    asm volatile("s_waitcnt vmcnt(0)" ::: "memory");        // next slabs landed
    __builtin_amdgcn_s_barrier();                           // (3)
  }

  // ---------------- epilogue ----------------
  float iv = 0.f;
  if (dh == 0) {
    iv = 1.0f / lrow;
    if (lane < 32) {
      m_part[ch * kB + q0 + qb * 32 + c] = mrow;
      l_part[ch * kB + q0 + qb * 32 + c] = lrow;
      facl[qb * 32 + c] = iv;
    }
  }
  asm volatile("s_waitcnt lgkmcnt(0)" ::: "memory");
  __builtin_amdgcn_s_barrier();
  if (dh == 1) iv = facl[qb * 32 + c];

  const size_t prow = ((size_t)ch * kB + q0 + qb * 32 + c) * 512;
  #pragma unroll
  for (int cf = 0; cf < 8; cf++) {
    const int C = dh * 256 + cf * 32;
    #pragma unroll
    for (int a = 0; a < 4; a++) {
      unsigned lo = pk2(O[cf][4 * a + 0] * iv, O[cf][4 * a + 1] * iv);
      unsigned hi = pk2(O[cf][4 * a + 2] * iv, O[cf][4 * a + 3] * iv);
      u32x2 v = {lo, hi};
      *(u32x2*)(pvn + prow + C + 8 * a + 4 * h) = v;
    }
  }
}

// ---------------------------------------------------------------------------
// Kernel 3: combine:  out = proj + alpha * (sum_c g_c l_c pvn_c) / (sum_c g_c l_c)
// ---------------------------------------------------------------------------
__global__ __launch_bounds__(256) void combine_kernel(
    const float* __restrict__ proj, const float* __restrict__ m_part,
    const float* __restrict__ l_part, const f16* __restrict__ pvn,
    const float* __restrict__ alpha_p, float* __restrict__ out)
{
  const int row = blockIdx.x;
  const int t = threadIdx.x;
  const float alpha = alpha_p[0];
  float M = -INFINITY;
  #pragma unroll
  for (int c = 0; c < kNch; c++) M = fmaxf(M, m_part[c * kB + row]);
  float gl[kNch];
  float T = 0.f;
  #pragma unroll
  for (int c = 0; c < kNch; c++) {
    gl[c] = __expf(m_part[c * kB + row] - M) * l_part[c * kB + row];
    T += gl[c];
  }
  const float s = alpha / T;
  #pragma unroll
  for (int half = 0; half < 2; half++) {
    const int col = t + half * 256;
    float acc = 0.f;
    #pragma unroll
    for (int c = 0; c < kNch; c++)
      acc += gl[c] * (float)pvn[((size_t)c * kB + row) * 512 + col];
    out[(size_t)row * 512 + col] = proj[(size_t)row * 512 + col] + acc * s;
  }
}

// ---------------------------------------------------------------------------
extern "C" void kernel_launch(void* const* d_in, const int* in_sizes, int n_in,
                              void* d_out, int out_size, void* d_ws, size_t ws_size,
                              hipStream_t stream) {
  (void)in_sizes; (void)n_in; (void)out_size; (void)ws_size;
  const float* x     = (const float*)d_in[0];
  const float* W     = (const float*)d_in[1];
  const float* bias  = (const float*)d_in[2];
  const float* cimg  = (const float*)d_in[3];
  const float* ctxt  = (const float*)d_in[4];
  const float* beta  = (const float*)d_in[5];
  const float* alpha = (const float*)d_in[6];
  float* out = (float*)d_out;
  char* ws = (char*)d_ws;

  float* proj = (float*)(ws + WS_PROJ);
  f16*   qhi  = (f16*)(ws + WS_QHI);
  float* mp   = (float*)(ws + WS_M);
  float* lp   = (float*)(ws + WS_L);
  f16*   pvn  = (f16*)(ws + WS_PV);
  f16*   K16  = (f16*)(ws + WS_K16);
  f16*   Vt16 = (f16*)(ws + WS_VT);

  hipFuncSetAttribute((const void*)attn_kernel,
                      hipFuncAttributeMaxDynamicSharedMemorySize, LDS_SZ);

  convk_kernel<<<(kKRows * 512 / 8 + 255) / 256, 256, 0, stream>>>(cimg, K16);
  transv_kernel<<<dim3(kVStride / 64, 8, kNch), 256, 0, stream>>>(ctxt, Vt16);
  gemm1_kernel<<<dim3(32, 8), 256, 0, stream>>>(x, W, bias, proj, qhi);
  attn_kernel<<<256, 512, LDS_SZ, stream>>>(K16, Vt16, qhi, beta, mp, lp, pvn);
  combine_kernel<<<2048, 256, 0, stream>>>(proj, mp, lp, pvn, alpha, out);
}

// Round 4
// 388.298 us; speedup vs baseline: 3.1853x; 1.0528x over previous
//
#include <hip/hip_runtime.h>
#include <hip/hip_bf16.h>
#include <math.h>

typedef _Float16 f16;
typedef __attribute__((ext_vector_type(8))) _Float16 f16x8;
typedef __attribute__((ext_vector_type(4))) float f32x4;
typedef __attribute__((ext_vector_type(16))) float f32x16;
typedef __attribute__((ext_vector_type(4))) unsigned int u32x4;
typedef __attribute__((ext_vector_type(2))) unsigned int u32x2;

#define MFMA16(A, B, C) __builtin_amdgcn_mfma_f32_16x16x32_f16(A, B, C, 0, 0, 0)
#define MFMA32(A, B, C) __builtin_amdgcn_mfma_f32_32x32x16_f16(A, B, C, 0, 0, 0)
#define AS1 __attribute__((address_space(1)))
#define AS3 __attribute__((address_space(3)))

__device__ __forceinline__ void gld16(const char* g, char* l) {
  __builtin_amdgcn_global_load_lds((const AS1 void*)g, (AS3 void*)l, 16, 0, 0);
}

__device__ __forceinline__ unsigned pk2(float a, float b) {
  f16 x = (f16)a, y = (f16)b;
  unsigned short ux = __builtin_bit_cast(unsigned short, x);
  unsigned short uy = __builtin_bit_cast(unsigned short, y);
  return (unsigned)ux | ((unsigned)uy << 16);
}

namespace {
constexpr int kB = 2048;
constexpr int kNch = 16, kChunk = 3125, kNit = 98;   // 98*32 = 3136 >= 3125
constexpr int kKRows = 50176;                        // padded K16 rows
constexpr int kVStride = 3200;                       // padded keys per chunk in Vt16
// workspace layout (bytes)
constexpr size_t WS_PROJ = 0;                                   // [2048][512] f32
constexpr size_t WS_QHI  = WS_PROJ + (size_t)2048 * 512 * 4;    // [2048][512] f16
constexpr size_t WS_M    = WS_QHI + (size_t)2048 * 512 * 2;     // [16][2048] f32
constexpr size_t WS_L    = WS_M + (size_t)kNch * kB * 4;        // [16][2048] f32
constexpr size_t WS_PV   = WS_L + (size_t)kNch * kB * 4;        // [16][2048][512] f16 (normalized)
constexpr size_t WS_K16  = WS_PV + (size_t)kNch * kB * 512 * 2; // [50176][512] f16
constexpr size_t WS_VT   = WS_K16 + (size_t)kKRows * 512 * 2;   // [16][512][3200] f16
// attn LDS layout
constexpr int LDS_K0 = 0, LDS_K1 = 33280;            // 2 x (32 rows x 1040B)
constexpr int LDS_V0 = 66560, LDS_V1 = 99328;        // 2 x (512 cols x 64B)
constexpr int LDS_SXP = 132096;                      // 4 x 4096 (S-partial / P-frags)
constexpr int LDS_FAC = 148480;                      // 128 f32
constexpr int LDS_FLG = 148992;                      // 4 int
constexpr int LDS_SZ  = 149504;
}

// ---------------------------------------------------------------------------
// K16: f16 copy of cache_image_features, rows >= 50000 zero-filled.
// ---------------------------------------------------------------------------
__global__ __launch_bounds__(256) void convk_kernel(const float* __restrict__ src,
                                                    f16* __restrict__ dst) {
  const size_t e = ((size_t)blockIdx.x * 256 + threadIdx.x) * 8;
  const int row = (int)(e >> 9);
  float4 a = make_float4(0.f, 0.f, 0.f, 0.f), b = a;
  if (row < 50000) {
    a = *(const float4*)(src + e);
    b = *(const float4*)(src + e + 4);
  }
  f16x8 h;
  h[0] = (f16)a.x; h[1] = (f16)a.y; h[2] = (f16)a.z; h[3] = (f16)a.w;
  h[4] = (f16)b.x; h[5] = (f16)b.y; h[6] = (f16)b.z; h[7] = (f16)b.w;
  *(f16x8*)(dst + e) = h;
}

// ---------------------------------------------------------------------------
// Vt16[ch][col][key] f16 transpose of cache_text_features; pad keys zeroed.
// ---------------------------------------------------------------------------
__global__ __launch_bounds__(256) void transv_kernel(const float* __restrict__ Vf,
                                                     f16* __restrict__ Vt) {
  __shared__ float tile[64][65];
  const int kt = blockIdx.x, colt = blockIdx.y, ch = blockIdx.z;
  const int t = threadIdx.x;
  const int kbase = kt * 64, col0 = colt * 64;
  {
    const int key = t >> 2, cseg = (t & 3) * 16;
    const int kk = kbase + key;
    float4 v0 = make_float4(0.f, 0.f, 0.f, 0.f), v1 = v0, v2 = v0, v3 = v0;
    if (kk < kChunk) {
      const float* s = Vf + (size_t)(ch * kChunk + kk) * 512 + col0 + cseg;
      v0 = *(const float4*)(s);
      v1 = *(const float4*)(s + 4);
      v2 = *(const float4*)(s + 8);
      v3 = *(const float4*)(s + 12);
    }
    float* tr = &tile[key][cseg];
    tr[0] = v0.x;  tr[1] = v0.y;  tr[2] = v0.z;  tr[3] = v0.w;
    tr[4] = v1.x;  tr[5] = v1.y;  tr[6] = v1.z;  tr[7] = v1.w;
    tr[8] = v2.x;  tr[9] = v2.y;  tr[10] = v2.z; tr[11] = v2.w;
    tr[12] = v3.x; tr[13] = v3.y; tr[14] = v3.z; tr[15] = v3.w;
  }
  __syncthreads();
  {
    const int col = t >> 2, kw = (t & 3) * 16;
    f16x8 h0, h1;
    #pragma unroll
    for (int u = 0; u < 8; u++) h0[u] = (f16)tile[kw + u][col];
    #pragma unroll
    for (int u = 0; u < 8; u++) h1[u] = (f16)tile[kw + 8 + u][col];
    f16* d = Vt + ((size_t)ch * 512 + col0 + col) * kVStride + kbase + kw;
    *(f16x8*)(d) = h0;
    *(f16x8*)(d + 8) = h1;
  }
}

// ---------------------------------------------------------------------------
// Kernel 1: proj = x @ W^T + b   (f16 x3-split MFMA, near-fp32 accuracy)
// ---------------------------------------------------------------------------
__global__ __launch_bounds__(256) void gemm1_kernel(
    const float* __restrict__ x, const float* __restrict__ W,
    const float* __restrict__ bias, float* __restrict__ proj,
    f16* __restrict__ qhi)
{
  __shared__ f16 xh[2][64][40], xl[2][64][40], wh[2][64][40], wl[2][64][40];
  const int t = threadIdx.x;
  const int lane = t & 63, w = t >> 6;
  const int wr = w >> 1, wc = w & 1;
  const int g = lane >> 4, j = lane & 15;
  const int m0 = blockIdx.x * 64, n0 = blockIdx.y * 64;
  const int srow = t >> 2;
  const int soff = (t & 3) * 8;

  const f32x4 fzero = {0.f, 0.f, 0.f, 0.f};
  f32x4 acc[2][2], acc2[2][2];
  #pragma unroll
  for (int a = 0; a < 2; a++)
    #pragma unroll
    for (int bb = 0; bb < 2; bb++) { acc[a][bb] = fzero; acc2[a][bb] = fzero; }

  auto stage = [&](int k0s, int buf) {
    const float* xs  = x + (size_t)(m0 + srow) * 1024 + k0s + soff;
    const float* wsr = W + (size_t)(n0 + srow) * 1024 + k0s + soff;
    f16x8 hx, lx, hw, lw;
    #pragma unroll
    for (int i = 0; i < 8; i++) {
      float v = xs[i];
      f16 h = (f16)v;
      hx[i] = h;
      lx[i] = (f16)((v - (float)h) * 2048.0f);
      float u = wsr[i];
      f16 hu = (f16)u;
      hw[i] = hu;
      lw[i] = (f16)((u - (float)hu) * 2048.0f);
    }
    *(f16x8*)&xh[buf][srow][soff] = hx;
    *(f16x8*)&xl[buf][srow][soff] = lx;
    *(f16x8*)&wh[buf][srow][soff] = hw;
    *(f16x8*)&wl[buf][srow][soff] = lw;
  };

  stage(0, 0);
  for (int ks = 0; ks < 32; ks++) {
    __syncthreads();
    if (ks < 31) stage((ks + 1) * 32, (ks + 1) & 1);
    const int buf = ks & 1;
    f16x8 ah[2], al[2], bh[2], bl[2];
    #pragma unroll
    for (int mf = 0; mf < 2; mf++) {
      const int r = wr * 32 + mf * 16 + j;
      ah[mf] = *(const f16x8*)&xh[buf][r][g * 8];
      al[mf] = *(const f16x8*)&xl[buf][r][g * 8];
      const int cc = wc * 32 + mf * 16 + j;
      bh[mf] = *(const f16x8*)&wh[buf][cc][g * 8];
      bl[mf] = *(const f16x8*)&wl[buf][cc][g * 8];
    }
    #pragma unroll
    for (int mf = 0; mf < 2; mf++)
      #pragma unroll
      for (int nf = 0; nf < 2; nf++) {
        acc[mf][nf]  = MFMA16(ah[mf], bh[nf], acc[mf][nf]);
        acc2[mf][nf] = MFMA16(ah[mf], bl[nf], acc2[mf][nf]);
        acc2[mf][nf] = MFMA16(al[mf], bh[nf], acc2[mf][nf]);
      }
  }

  #pragma unroll
  for (int mf = 0; mf < 2; mf++)
    #pragma unroll
    for (int nf = 0; nf < 2; nf++)
      #pragma unroll
      for (int r = 0; r < 4; r++) {
        const int m = m0 + wr * 32 + mf * 16 + g * 4 + r;
        const int n = n0 + wc * 32 + nf * 16 + j;
        float p = acc[mf][nf][r] + acc2[mf][nf][r] * (1.0f / 2048.0f) + bias[n];
        proj[(size_t)m * 512 + n] = p;
        qhi[(size_t)m * 512 + n] = (f16)p;
      }
}

// ---------------------------------------------------------------------------
// Kernel 2: flash attention partial. QK/softmax roles (qb=w&3, dh=w>>2) as
// before; PV roles (qp=w&1, cq=w>>1) reuse each V A-frag for 2 q-blocks.
// Defer-max (THR=8) skips O-rescale most iters. V swizzle = ((c>>1)&3) quarter
// XOR (min-conflict). 3 barriers/iter, double-buffered K/V via global_load_lds.
// ---------------------------------------------------------------------------
__global__ __launch_bounds__(512, 2) void attn_kernel(
    const f16* __restrict__ K16, const f16* __restrict__ Vt16,
    const f16* __restrict__ qhi_ws, const float* __restrict__ beta_p,
    float* __restrict__ m_part, float* __restrict__ l_part,
    f16* __restrict__ pvn)
{
  extern __shared__ char smem[];
  const int t = threadIdx.x, lane = t & 63, w = t >> 6;
  const int c = lane & 31, h = lane >> 5;
  const int qb = w & 3, dh = w >> 2;     // QK / softmax roles
  const int qp = w & 1, cq = w >> 1;     // PV roles (cq 0..3)
  const int ch = blockIdx.x & 15, qt = blockIdx.x >> 4;
  const int q0 = qt * 128;
  const float beta = beta_p[0];

  char* const Kb0 = smem + LDS_K0;
  char* const Kb1 = smem + LDS_K1;
  char* const Vb0 = smem + LDS_V0;
  char* const Vb1 = smem + LDS_V1;
  char* const SxPq = smem + LDS_SXP + qb * 4096;   // own-qb slot (S-partial / P)
  float* const facl = (float*)(smem + LDS_FAC);
  int* const flg = (int*)(smem + LDS_FLG);

  // ---- Q -> registers as B-frags: lane holds q-col = qb*32+c, k-chunk h*8.
  f16x8 Qf[16];
  {
    const f16* qsrc = qhi_ws + (size_t)(q0 + qb * 32 + c) * 512 + dh * 256 + h * 8;
    #pragma unroll
    for (int i = 0; i < 16; i++) Qf[i] = *(const f16x8*)(qsrc + i * 16);
  }
  __builtin_amdgcn_sched_barrier(0);

  const char* const Kg = (const char*)K16 + (size_t)(ch * kChunk) * 1024;
  const char* const Vg = (const char*)Vt16 + (size_t)ch * 512 * (kVStride * 2);
  // pre-swizzled V source: 16B-chunk ^ ((col>>1)&3), col = u*128+(t>>2)
  const int vlo = (((lane & 3) ^ ((lane >> 3) & 3)) << 4);

  auto stageK = [&](int it, char* dstbuf) {
    const char* src = Kg + (size_t)(it * 32 + w * 4) * 1024 + lane * 16;
    char* dst = dstbuf + (w * 4) * 1040 + lane * 16;
    #pragma unroll
    for (int u = 0; u < 4; u++) gld16(src + u * 1024, dst + u * 1040);
  };
  auto stageV = [&](int it, char* dstbuf) {
    const char* src = Vg + (size_t)(w * 64 + (lane >> 2)) * (kVStride * 2) + it * 64 + vlo;
    char* dst = dstbuf + (w * 64) * 64 + lane * 16;
    #pragma unroll
    for (int u = 0; u < 4; u++)
      gld16(src + (size_t)(u * 16) * (kVStride * 2), dst + u * 1024);
  };

  // LDS read offsets
  const int kroff = c * 1040 + dh * 512 + h * 16;          // QK A-frag base
  const int vbase = (cq * 128 + c) * 64;                   // PV A-frag base
  const int vswz = ((c >> 1) & 3) << 4;
  const int voff0 = (0 + h * 16) ^ vswz;                   // ks=0
  const int voff1 = (32 + h * 16) ^ vswz;                  // ks=1
  // P slots for PV role: q-blocks 2qp, 2qp+1
  const char* const slotA = smem + LDS_SXP + (2 * qp) * 4096 + lane * 16;
  const char* const slotB = smem + LDS_SXP + (2 * qp + 1) * 4096 + lane * 16;

  f32x16 O[2][4];
  #pragma unroll
  for (int ql = 0; ql < 2; ql++)
    #pragma unroll
    for (int cb = 0; cb < 4; cb++)
      #pragma unroll
      for (int r = 0; r < 16; r++) O[ql][cb][r] = 0.f;
  float mrow = -INFINITY, lrow = 0.f;

  stageK(0, Kb0);
  stageV(0, Vb0);
  asm volatile("s_waitcnt vmcnt(0)" ::: "memory");
  __builtin_amdgcn_s_barrier();

  for (int it = 0; it < kNit; it++) {
    const int p = it & 1;
    const char* const Kp = (p ? Kb1 : Kb0) + kroff;
    const char* const Vp = (p ? Vb1 : Vb0) + vbase;
    if (it + 1 < kNit) {
      stageK(it + 1, p ? Kb0 : Kb1);
      stageV(it + 1, p ? Vb0 : Vb1);
    }

    // ---------------- QK: S^T = K . Q over this wave's d-half -------------
    f32x16 S;
    #pragma unroll
    for (int r = 0; r < 16; r++) S[r] = 0.f;
    __builtin_amdgcn_s_setprio(1);
    #pragma unroll
    for (int i = 0; i < 16; i++) {
      f16x8 a = *(const f16x8*)(Kp + i * 32);
      S = MFMA32(a, Qf[i], S);
    }
    __builtin_amdgcn_s_setprio(0);

    if (dh == 1) {  // write d-partial (f32), lane-major, conflict-free
      f32x4 v0 = {S[0], S[1], S[2], S[3]};
      f32x4 v1 = {S[4], S[5], S[6], S[7]};
      f32x4 v2 = {S[8], S[9], S[10], S[11]};
      f32x4 v3 = {S[12], S[13], S[14], S[15]};
      *(f32x4*)(SxPq + 0 * 1024 + lane * 16) = v0;
      *(f32x4*)(SxPq + 1 * 1024 + lane * 16) = v1;
      *(f32x4*)(SxPq + 2 * 1024 + lane * 16) = v2;
      *(f32x4*)(SxPq + 3 * 1024 + lane * 16) = v3;
    }
    asm volatile("s_waitcnt lgkmcnt(0)" ::: "memory");
    __builtin_amdgcn_s_barrier();                           // (1)

    if (dh == 0) {
      // combine partner d-half
      #pragma unroll
      for (int cc = 0; cc < 4; cc++) {
        f32x4 v = *(const f32x4*)(SxPq + cc * 1024 + lane * 16);
        S[4 * cc + 0] += v.x; S[4 * cc + 1] += v.y;
        S[4 * cc + 2] += v.z; S[4 * cc + 3] += v.w;
      }
      #pragma unroll
      for (int r = 0; r < 16; r++) S[r] *= beta;
      if (it == kNit - 1) {
        #pragma unroll
        for (int r = 0; r < 16; r++) {
          const int key = it * 32 + (r & 3) + 8 * (r >> 2) + 4 * h;
          if (key >= kChunk) S[r] = -INFINITY;
        }
      }
      float pm = S[0];
      #pragma unroll
      for (int r = 1; r < 16; r++) pm = fmaxf(pm, S[r]);
      pm = fmaxf(pm, __shfl_xor(pm, 32));
      const int need = __any(pm > mrow + 8.0f);             // defer-max (T13)
      float fc = 1.0f;
      if (need) {
        const float mn = fmaxf(mrow, pm);
        fc = __expf(mrow - mn);
        mrow = mn;
      }
      float pr[16], rs = 0.f;
      #pragma unroll
      for (int r = 0; r < 16; r++) { pr[r] = __expf(S[r] - mrow); rs += pr[r]; }
      rs += __shfl_xor(rs, 32);
      lrow = lrow * fc + rs;
      // build PV B-frags (pack + half-swap + select), write to own slot
      unsigned pA0 = pk2(pr[0], pr[1]),  pA1 = pk2(pr[2], pr[3]);
      unsigned pB0 = pk2(pr[4], pr[5]),  pB1 = pk2(pr[6], pr[7]);
      unsigned pC0 = pk2(pr[8], pr[9]),  pC1 = pk2(pr[10], pr[11]);
      unsigned pD0 = pk2(pr[12], pr[13]), pD1 = pk2(pr[14], pr[15]);
      unsigned sA0 = __shfl_xor(pA0, 32), sA1 = __shfl_xor(pA1, 32);
      unsigned sB0 = __shfl_xor(pB0, 32), sB1 = __shfl_xor(pB1, 32);
      unsigned sC0 = __shfl_xor(pC0, 32), sC1 = __shfl_xor(pC1, 32);
      unsigned sD0 = __shfl_xor(pD0, 32), sD1 = __shfl_xor(pD1, 32);
      u32x4 B0, B1;
      B0[0] = h ? sB0 : pA0;  B0[1] = h ? sB1 : pA1;
      B0[2] = h ? pB0 : sA0;  B0[3] = h ? pB1 : sA1;
      B1[0] = h ? sD0 : pC0;  B1[1] = h ? sD1 : pC1;
      B1[2] = h ? pD0 : sC0;  B1[3] = h ? pD1 : sC1;
      *(u32x4*)(SxPq + 0 * 1024 + lane * 16) = B0;
      *(u32x4*)(SxPq + 1 * 1024 + lane * 16) = B1;
      if (need && h == 0) facl[qb * 32 + c] = fc;
      if (lane == 0) flg[qb] = need;
    }
    asm volatile("s_waitcnt lgkmcnt(0)" ::: "memory");
    __builtin_amdgcn_s_barrier();                           // (2)

    // ---------------- PV role: O^T += V^T . P^T (2 q-blocks per V-read) ---
    const int f0 = flg[2 * qp];
    const int f1 = flg[2 * qp + 1];
    const f16x8 pb00 = *(const f16x8*)(slotA);
    const f16x8 pb01 = *(const f16x8*)(slotA + 1024);
    const f16x8 pb10 = *(const f16x8*)(slotB);
    const f16x8 pb11 = *(const f16x8*)(slotB + 1024);
    if (f0) {
      const float fc0 = facl[(2 * qp) * 32 + c];
      #pragma unroll
      for (int cb = 0; cb < 4; cb++)
        #pragma unroll
        for (int r = 0; r < 16; r++) O[0][cb][r] *= fc0;
    }
    if (f1) {
      const float fc1 = facl[(2 * qp + 1) * 32 + c];
      #pragma unroll
      for (int cb = 0; cb < 4; cb++)
        #pragma unroll
        for (int r = 0; r < 16; r++) O[1][cb][r] *= fc1;
    }
    __builtin_amdgcn_s_setprio(1);
    #pragma unroll
    for (int cb = 0; cb < 4; cb++) {
      f16x8 a0 = *(const f16x8*)(Vp + cb * 2048 + voff0);
      f16x8 a1 = *(const f16x8*)(Vp + cb * 2048 + voff1);
      O[0][cb] = MFMA32(a0, pb00, O[0][cb]);
      O[0][cb] = MFMA32(a1, pb01, O[0][cb]);
      O[1][cb] = MFMA32(a0, pb10, O[1][cb]);
      O[1][cb] = MFMA32(a1, pb11, O[1][cb]);
    }
    __builtin_amdgcn_s_setprio(0);

    asm volatile("s_waitcnt vmcnt(0)" ::: "memory");        // next slabs landed
    __builtin_amdgcn_s_barrier();                           // (3)
  }

  // ---------------- epilogue ----------------
  if (dh == 0) {
    const float iv = 1.0f / lrow;
    if (lane < 32) {
      m_part[ch * kB + q0 + qb * 32 + c] = mrow;
      l_part[ch * kB + q0 + qb * 32 + c] = lrow;
      facl[qb * 32 + c] = iv;
    }
  }
  asm volatile("s_waitcnt lgkmcnt(0)" ::: "memory");
  __builtin_amdgcn_s_barrier();
  const float iv0 = facl[(2 * qp) * 32 + c];
  const float iv1 = facl[(2 * qp + 1) * 32 + c];

  const size_t pvb = ((size_t)ch * kB + q0) * 512;
  #pragma unroll
  for (int ql = 0; ql < 2; ql++) {
    const int qrow = (2 * qp + ql) * 32 + c;
    const float iv = ql ? iv1 : iv0;
    #pragma unroll
    for (int cb = 0; cb < 4; cb++) {
      const int C = cq * 128 + cb * 32;
      #pragma unroll
      for (int a = 0; a < 4; a++) {
        unsigned lo = pk2(O[ql][cb][4 * a + 0] * iv, O[ql][cb][4 * a + 1] * iv);
        unsigned hi = pk2(O[ql][cb][4 * a + 2] * iv, O[ql][cb][4 * a + 3] * iv);
        u32x2 v = {lo, hi};
        *(u32x2*)(pvn + pvb + (size_t)qrow * 512 + C + 8 * a + 4 * h) = v;
      }
    }
  }
}

// ---------------------------------------------------------------------------
// Kernel 3: combine:  out = proj + alpha * (sum_c g_c l_c pvn_c) / (sum_c g_c l_c)
// ---------------------------------------------------------------------------
__global__ __launch_bounds__(256) void combine_kernel(
    const float* __restrict__ proj, const float* __restrict__ m_part,
    const float* __restrict__ l_part, const f16* __restrict__ pvn,
    const float* __restrict__ alpha_p, float* __restrict__ out)
{
  const int row = blockIdx.x;
  const int t = threadIdx.x;
  const float alpha = alpha_p[0];
  float M = -INFINITY;
  #pragma unroll
  for (int c = 0; c < kNch; c++) M = fmaxf(M, m_part[c * kB + row]);
  float gl[kNch];
  float T = 0.f;
  #pragma unroll
  for (int c = 0; c < kNch; c++) {
    gl[c] = __expf(m_part[c * kB + row] - M) * l_part[c * kB + row];
    T += gl[c];
  }
  const float s = alpha / T;
  #pragma unroll
  for (int half = 0; half < 2; half++) {
    const int col = t + half * 256;
    float acc = 0.f;
    #pragma unroll
    for (int c = 0; c < kNch; c++)
      acc += gl[c] * (float)pvn[((size_t)c * kB + row) * 512 + col];
    out[(size_t)row * 512 + col] = proj[(size_t)row * 512 + col] + acc * s;
  }
}

// ---------------------------------------------------------------------------
extern "C" void kernel_launch(void* const* d_in, const int* in_sizes, int n_in,
                              void* d_out, int out_size, void* d_ws, size_t ws_size,
                              hipStream_t stream) {
  (void)in_sizes; (void)n_in; (void)out_size; (void)ws_size;
  const float* x     = (const float*)d_in[0];
  const float* W     = (const float*)d_in[1];
  const float* bias  = (const float*)d_in[2];
  const float* cimg  = (const float*)d_in[3];
  const float* ctxt  = (const float*)d_in[4];
  const float* beta  = (const float*)d_in[5];
  const float* alpha = (const float*)d_in[6];
  float* out = (float*)d_out;
  char* ws = (char*)d_ws;

  float* proj = (float*)(ws + WS_PROJ);
  f16*   qhi  = (f16*)(ws + WS_QHI);
  float* mp   = (float*)(ws + WS_M);
  float* lp   = (float*)(ws + WS_L);
  f16*   pvn  = (f16*)(ws + WS_PV);
  f16*   K16  = (f16*)(ws + WS_K16);
  f16*   Vt16 = (f16*)(ws + WS_VT);

  hipFuncSetAttribute((const void*)attn_kernel,
                      hipFuncAttributeMaxDynamicSharedMemorySize, LDS_SZ);

  convk_kernel<<<(kKRows * 512 / 8 + 255) / 256, 256, 0, stream>>>(cimg, K16);
  transv_kernel<<<dim3(kVStride / 64, 8, kNch), 256, 0, stream>>>(ctxt, Vt16);
  gemm1_kernel<<<dim3(32, 8), 256, 0, stream>>>(x, W, bias, proj, qhi);
  attn_kernel<<<256, 512, LDS_SZ, stream>>>(K16, Vt16, qhi, beta, mp, lp, pvn);
  combine_kernel<<<2048, 256, 0, stream>>>(proj, mp, lp, pvn, alpha, out);
}

// Round 5
// 371.230 us; speedup vs baseline: 3.3318x; 1.0460x over previous
//
#include <hip/hip_runtime.h>
#include <hip/hip_bf16.h>
#include <math.h>

typedef _Float16 f16;
typedef __attribute__((ext_vector_type(8))) _Float16 f16x8;
typedef __attribute__((ext_vector_type(4))) float f32x4;
typedef __attribute__((ext_vector_type(16))) float f32x16;
typedef __attribute__((ext_vector_type(4))) unsigned int u32x4;
typedef __attribute__((ext_vector_type(2))) unsigned int u32x2;

#define MFMA16(A, B, C) __builtin_amdgcn_mfma_f32_16x16x32_f16(A, B, C, 0, 0, 0)
#define MFMA32(A, B, C) __builtin_amdgcn_mfma_f32_32x32x16_f16(A, B, C, 0, 0, 0)
#define AS1 __attribute__((address_space(1)))
#define AS3 __attribute__((address_space(3)))

__device__ __forceinline__ void gld16(const char* g, char* l) {
  __builtin_amdgcn_global_load_lds((const AS1 void*)g, (AS3 void*)l, 16, 0, 0);
}

__device__ __forceinline__ unsigned pk2(float a, float b) {
  f16 x = (f16)a, y = (f16)b;
  unsigned short ux = __builtin_bit_cast(unsigned short, x);
  unsigned short uy = __builtin_bit_cast(unsigned short, y);
  return (unsigned)ux | ((unsigned)uy << 16);
}

namespace {
constexpr int kB = 2048;
constexpr int kNch = 16, kChunk = 3125, kNit = 98;   // 98*32 = 3136 >= 3125
constexpr int kKRows = 50176;                        // padded K16 rows
constexpr int kVStride = 3200;                       // padded keys per chunk in Vt16
// workspace layout (bytes)
constexpr size_t WS_PROJ = 0;                                   // [2048][512] f32
constexpr size_t WS_QHI  = WS_PROJ + (size_t)2048 * 512 * 4;    // [2048][512] f16
constexpr size_t WS_M    = WS_QHI + (size_t)2048 * 512 * 2;     // [16][2048] f32
constexpr size_t WS_L    = WS_M + (size_t)kNch * kB * 4;        // [16][2048] f32
constexpr size_t WS_PV   = WS_L + (size_t)kNch * kB * 4;        // [16][2048][512] f16 (normalized)
constexpr size_t WS_K16  = WS_PV + (size_t)kNch * kB * 512 * 2; // [50176][512] f16
constexpr size_t WS_VT   = WS_K16 + (size_t)kKRows * 512 * 2;   // [16][512][3200] f16
// attn LDS layout
constexpr int LDS_K0 = 0, LDS_K1 = 33280;            // 2 x (32 rows x 1040B)
constexpr int LDS_V0 = 66560, LDS_V1 = 99328;        // 2 x (512 cols x 64B)
constexpr int LDS_S  = 132096;                       // 4 x 4096 (S-partial exchange)
constexpr int LDS_P  = 148480;                       // 4 x 2048 (P B-frags)
constexpr int LDS_FAC = 156672;                      // 128 f32
constexpr int LDS_FLG = 157184;                      // 4 int
constexpr int LDS_SZ  = 157696;
}

// ---------------------------------------------------------------------------
// K16: f16 copy of cache_image_features, rows >= 50000 zero-filled.
// ---------------------------------------------------------------------------
__global__ __launch_bounds__(256) void convk_kernel(const float* __restrict__ src,
                                                    f16* __restrict__ dst) {
  const size_t e = ((size_t)blockIdx.x * 256 + threadIdx.x) * 8;
  const int row = (int)(e >> 9);
  float4 a = make_float4(0.f, 0.f, 0.f, 0.f), b = a;
  if (row < 50000) {
    a = *(const float4*)(src + e);
    b = *(const float4*)(src + e + 4);
  }
  f16x8 h;
  h[0] = (f16)a.x; h[1] = (f16)a.y; h[2] = (f16)a.z; h[3] = (f16)a.w;
  h[4] = (f16)b.x; h[5] = (f16)b.y; h[6] = (f16)b.z; h[7] = (f16)b.w;
  *(f16x8*)(dst + e) = h;
}

// ---------------------------------------------------------------------------
// Vt16[ch][col][key] f16 transpose of cache_text_features; pad keys zeroed.
// ---------------------------------------------------------------------------
__global__ __launch_bounds__(256) void transv_kernel(const float* __restrict__ Vf,
                                                     f16* __restrict__ Vt) {
  __shared__ float tile[64][65];
  const int kt = blockIdx.x, colt = blockIdx.y, ch = blockIdx.z;
  const int t = threadIdx.x;
  const int kbase = kt * 64, col0 = colt * 64;
  {
    const int key = t >> 2, cseg = (t & 3) * 16;
    const int kk = kbase + key;
    float4 v0 = make_float4(0.f, 0.f, 0.f, 0.f), v1 = v0, v2 = v0, v3 = v0;
    if (kk < kChunk) {
      const float* s = Vf + (size_t)(ch * kChunk + kk) * 512 + col0 + cseg;
      v0 = *(const float4*)(s);
      v1 = *(const float4*)(s + 4);
      v2 = *(const float4*)(s + 8);
      v3 = *(const float4*)(s + 12);
    }
    float* tr = &tile[key][cseg];
    tr[0] = v0.x;  tr[1] = v0.y;  tr[2] = v0.z;  tr[3] = v0.w;
    tr[4] = v1.x;  tr[5] = v1.y;  tr[6] = v1.z;  tr[7] = v1.w;
    tr[8] = v2.x;  tr[9] = v2.y;  tr[10] = v2.z; tr[11] = v2.w;
    tr[12] = v3.x; tr[13] = v3.y; tr[14] = v3.z; tr[15] = v3.w;
  }
  __syncthreads();
  {
    const int col = t >> 2, kw = (t & 3) * 16;
    f16x8 h0, h1;
    #pragma unroll
    for (int u = 0; u < 8; u++) h0[u] = (f16)tile[kw + u][col];
    #pragma unroll
    for (int u = 0; u < 8; u++) h1[u] = (f16)tile[kw + 8 + u][col];
    f16* d = Vt + ((size_t)ch * 512 + col0 + col) * kVStride + kbase + kw;
    *(f16x8*)(d) = h0;
    *(f16x8*)(d + 8) = h1;
  }
}

// ---------------------------------------------------------------------------
// Kernel 1: proj = x @ W^T + b   (f16 x3-split MFMA, near-fp32 accuracy)
// ---------------------------------------------------------------------------
__global__ __launch_bounds__(256) void gemm1_kernel(
    const float* __restrict__ x, const float* __restrict__ W,
    const float* __restrict__ bias, float* __restrict__ proj,
    f16* __restrict__ qhi)
{
  __shared__ f16 xh[2][64][40], xl[2][64][40], wh[2][64][40], wl[2][64][40];
  const int t = threadIdx.x;
  const int lane = t & 63, w = t >> 6;
  const int wr = w >> 1, wc = w & 1;
  const int g = lane >> 4, j = lane & 15;
  const int m0 = blockIdx.x * 64, n0 = blockIdx.y * 64;
  const int srow = t >> 2;
  const int soff = (t & 3) * 8;

  const f32x4 fzero = {0.f, 0.f, 0.f, 0.f};
  f32x4 acc[2][2], acc2[2][2];
  #pragma unroll
  for (int a = 0; a < 2; a++)
    #pragma unroll
    for (int bb = 0; bb < 2; bb++) { acc[a][bb] = fzero; acc2[a][bb] = fzero; }

  auto stage = [&](int k0s, int buf) {
    const float* xs  = x + (size_t)(m0 + srow) * 1024 + k0s + soff;
    const float* wsr = W + (size_t)(n0 + srow) * 1024 + k0s + soff;
    f16x8 hx, lx, hw, lw;
    #pragma unroll
    for (int i = 0; i < 8; i++) {
      float v = xs[i];
      f16 h = (f16)v;
      hx[i] = h;
      lx[i] = (f16)((v - (float)h) * 2048.0f);
      float u = wsr[i];
      f16 hu = (f16)u;
      hw[i] = hu;
      lw[i] = (f16)((u - (float)hu) * 2048.0f);
    }
    *(f16x8*)&xh[buf][srow][soff] = hx;
    *(f16x8*)&xl[buf][srow][soff] = lx;
    *(f16x8*)&wh[buf][srow][soff] = hw;
    *(f16x8*)&wl[buf][srow][soff] = lw;
  };

  stage(0, 0);
  for (int ks = 0; ks < 32; ks++) {
    __syncthreads();
    if (ks < 31) stage((ks + 1) * 32, (ks + 1) & 1);
    const int buf = ks & 1;
    f16x8 ah[2], al[2], bh[2], bl[2];
    #pragma unroll
    for (int mf = 0; mf < 2; mf++) {
      const int r = wr * 32 + mf * 16 + j;
      ah[mf] = *(const f16x8*)&xh[buf][r][g * 8];
      al[mf] = *(const f16x8*)&xl[buf][r][g * 8];
      const int cc = wc * 32 + mf * 16 + j;
      bh[mf] = *(const f16x8*)&wh[buf][cc][g * 8];
      bl[mf] = *(const f16x8*)&wl[buf][cc][g * 8];
    }
    #pragma unroll
    for (int mf = 0; mf < 2; mf++)
      #pragma unroll
      for (int nf = 0; nf < 2; nf++) {
        acc[mf][nf]  = MFMA16(ah[mf], bh[nf], acc[mf][nf]);
        acc2[mf][nf] = MFMA16(ah[mf], bl[nf], acc2[mf][nf]);
        acc2[mf][nf] = MFMA16(al[mf], bh[nf], acc2[mf][nf]);
      }
  }

  #pragma unroll
  for (int mf = 0; mf < 2; mf++)
    #pragma unroll
    for (int nf = 0; nf < 2; nf++)
      #pragma unroll
      for (int r = 0; r < 4; r++) {
        const int m = m0 + wr * 32 + mf * 16 + g * 4 + r;
        const int n = n0 + wc * 32 + nf * 16 + j;
        float p = acc[mf][nf][r] + acc2[mf][nf][r] * (1.0f / 2048.0f) + bias[n];
        proj[(size_t)m * 512 + n] = p;
        qhi[(size_t)m * 512 + n] = (f16)p;
      }
}

// ---------------------------------------------------------------------------
// Kernel 2: flash attention partial, 2-phase pipelined:
//   phase B: PV(it-1) + QK(it) (dense MFMA/LDS phase), S-exchange write,
//            stageK(it+1)
//   phase A: stageV(it+1) issue, dh0 softmax + P-frag build
// 2 barriers/iter; vmcnt counted (4), never drained mid-loop.
// ---------------------------------------------------------------------------
__global__ __launch_bounds__(512, 2) void attn_kernel(
    const f16* __restrict__ K16, const f16* __restrict__ Vt16,
    const f16* __restrict__ qhi_ws, const float* __restrict__ beta_p,
    float* __restrict__ m_part, float* __restrict__ l_part,
    f16* __restrict__ pvn)
{
  extern __shared__ char smem[];
  const int t = threadIdx.x, lane = t & 63, w = t >> 6;
  const int c = lane & 31, h = lane >> 5;
  const int qb = w & 3, dh = w >> 2;     // QK / softmax roles
  const int qp = w & 1, cq = w >> 1;     // PV roles (cq 0..3)
  const int ch = blockIdx.x & 15, qt = blockIdx.x >> 4;
  const int q0 = qt * 128;
  const float beta = beta_p[0];

  char* const Kb0 = smem + LDS_K0;
  char* const Kb1 = smem + LDS_K1;
  char* const Vb0 = smem + LDS_V0;
  char* const Vb1 = smem + LDS_V1;
  char* const Sq  = smem + LDS_S + qb * 4096;   // own-qb S-partial slot
  char* const Pq  = smem + LDS_P + qb * 2048;   // own-qb P slot
  float* const facl = (float*)(smem + LDS_FAC);
  int* const flg = (int*)(smem + LDS_FLG);

  // ---- Q -> registers as B-frags: lane holds q-col = qb*32+c, k-chunk h*8.
  f16x8 Qf[16];
  {
    const f16* qsrc = qhi_ws + (size_t)(q0 + qb * 32 + c) * 512 + dh * 256 + h * 8;
    #pragma unroll
    for (int i = 0; i < 16; i++) Qf[i] = *(const f16x8*)(qsrc + i * 16);
  }
  __builtin_amdgcn_sched_barrier(0);

  const char* const Kg = (const char*)K16 + (size_t)(ch * kChunk) * 1024;
  const char* const Vg = (const char*)Vt16 + (size_t)ch * 512 * (kVStride * 2);
  // pre-swizzled V source chunk (matches read-side ((c>>1)&3) XOR)
  const int vlo = (((lane & 3) ^ ((lane >> 3) & 3)) << 4);

  auto stageK = [&](int it2, char* dstbuf) {
    const char* src = Kg + (size_t)(it2 * 32 + w * 4) * 1024 + lane * 16;
    char* dst = dstbuf + (w * 4) * 1040 + lane * 16;
    #pragma unroll
    for (int u = 0; u < 4; u++) gld16(src + u * 1024, dst + u * 1040);
  };
  auto stageV = [&](int it2, char* dstbuf) {
    const char* src = Vg + (size_t)(w * 64 + (lane >> 2)) * (kVStride * 2) + it2 * 64 + vlo;
    char* dst = dstbuf + (w * 4) * 1024 + lane * 16;
    #pragma unroll
    for (int u = 0; u < 4; u++)
      gld16(src + (size_t)(u * 16) * (kVStride * 2), dst + u * 1024);
  };

  // LDS read offsets (bank-conflict-engineered)
  const int kroff = c * 1040 + dh * 512 + h * 16;          // QK A-frag base
  const int vbase = (cq * 128 + c) * 64;                   // PV A-frag base
  const int vswz = ((c >> 1) & 3) << 4;
  const int voff0 = (0 + h * 16) ^ vswz;                   // keys 0..15
  const int voff1 = (32 + h * 16) ^ vswz;                  // keys 16..31
  const char* const slotA = smem + LDS_P + (2 * qp) * 2048 + lane * 16;
  const char* const slotB = smem + LDS_P + (2 * qp + 1) * 2048 + lane * 16;

  f32x16 O[2][4];
  #pragma unroll
  for (int ql = 0; ql < 2; ql++)
    #pragma unroll
    for (int cb = 0; cb < 4; cb++)
      #pragma unroll
      for (int r = 0; r < 16; r++) O[ql][cb][r] = 0.f;
  float mrow = -INFINITY, lrow = 0.f;

  // PV(prev) step: rescale (flag-gated) + 16 MFMA32 on V buffer `Vp`
  auto pvstep = [&](const char* Vp) {
    const int f0 = flg[2 * qp];
    const int f1 = flg[2 * qp + 1];
    const f16x8 pb00 = *(const f16x8*)(slotA);
    const f16x8 pb01 = *(const f16x8*)(slotA + 1024);
    const f16x8 pb10 = *(const f16x8*)(slotB);
    const f16x8 pb11 = *(const f16x8*)(slotB + 1024);
    if (f0) {
      const float fc0 = facl[(2 * qp) * 32 + c];
      #pragma unroll
      for (int cb = 0; cb < 4; cb++)
        #pragma unroll
        for (int r = 0; r < 16; r++) O[0][cb][r] *= fc0;
    }
    if (f1) {
      const float fc1 = facl[(2 * qp + 1) * 32 + c];
      #pragma unroll
      for (int cb = 0; cb < 4; cb++)
        #pragma unroll
        for (int r = 0; r < 16; r++) O[1][cb][r] *= fc1;
    }
    __builtin_amdgcn_s_setprio(1);
    #pragma unroll
    for (int cb = 0; cb < 4; cb++) {
      f16x8 a0 = *(const f16x8*)(Vp + cb * 2048 + voff0);
      f16x8 a1 = *(const f16x8*)(Vp + cb * 2048 + voff1);
      O[0][cb] = MFMA32(a0, pb00, O[0][cb]);
      O[0][cb] = MFMA32(a1, pb01, O[0][cb]);
      O[1][cb] = MFMA32(a0, pb10, O[1][cb]);
      O[1][cb] = MFMA32(a1, pb11, O[1][cb]);
    }
    __builtin_amdgcn_s_setprio(0);
  };

  // prologue: K0 + V0 in flight; wait K0 only (V0 needed first in B(1))
  stageK(0, Kb0);
  stageV(0, Vb0);
  asm volatile("s_waitcnt vmcnt(4)" ::: "memory");
  __builtin_amdgcn_s_barrier();

  for (int it = 0; it < kNit; it++) {
    const int p = it & 1;
    const char* const Kp = (p ? Kb1 : Kb0) + kroff;

    // ================= phase B: PV(it-1) + QK(it) =================
    if (it > 0) pvstep((p ? Vb0 : Vb1) + vbase);   // V[it-1] lives in buf p^1
    if (it + 1 < kNit) stageK(it + 1, p ? Kb0 : Kb1);

    f32x16 S;
    #pragma unroll
    for (int r = 0; r < 16; r++) S[r] = 0.f;
    __builtin_amdgcn_s_setprio(1);
    #pragma unroll
    for (int i = 0; i < 16; i++) {
      f16x8 a = *(const f16x8*)(Kp + i * 32);
      S = MFMA32(a, Qf[i], S);
    }
    __builtin_amdgcn_s_setprio(0);

    if (dh == 1) {  // write d-partial (f32), lane-major, conflict-free
      f32x4 v0 = {S[0], S[1], S[2], S[3]};
      f32x4 v1 = {S[4], S[5], S[6], S[7]};
      f32x4 v2 = {S[8], S[9], S[10], S[11]};
      f32x4 v3 = {S[12], S[13], S[14], S[15]};
      *(f32x4*)(Sq + 0 * 1024 + lane * 16) = v0;
      *(f32x4*)(Sq + 1 * 1024 + lane * 16) = v1;
      *(f32x4*)(Sq + 2 * 1024 + lane * 16) = v2;
      *(f32x4*)(Sq + 3 * 1024 + lane * 16) = v3;
    }
    asm volatile("s_waitcnt lgkmcnt(0)" ::: "memory");
    __builtin_amdgcn_s_barrier();                         // bar-beta

    // ================= phase A: stageV(it+1) + softmax(it) =========
    if (it + 1 < kNit) stageV(it + 1, p ? Vb0 : Vb1);     // after bar: safe vs PV reads

    if (dh == 0) {
      #pragma unroll
      for (int cc = 0; cc < 4; cc++) {
        f32x4 v = *(const f32x4*)(Sq + cc * 1024 + lane * 16);
        S[4 * cc + 0] += v.x; S[4 * cc + 1] += v.y;
        S[4 * cc + 2] += v.z; S[4 * cc + 3] += v.w;
      }
      #pragma unroll
      for (int r = 0; r < 16; r++) S[r] *= beta;
      if (it == kNit - 1) {
        #pragma unroll
        for (int r = 0; r < 16; r++) {
          const int key = it * 32 + (r & 3) + 8 * (r >> 2) + 4 * h;
          if (key >= kChunk) S[r] = -INFINITY;
        }
      }
      float pm = S[0];
      #pragma unroll
      for (int r = 1; r < 16; r++) pm = fmaxf(pm, S[r]);
      pm = fmaxf(pm, __shfl_xor(pm, 32));
      const int need = __any(pm > mrow + 8.0f);           // defer-max (T13)
      float fc = 1.0f;
      if (need) {
        const float mn = fmaxf(mrow, pm);
        fc = __expf(mrow - mn);
        mrow = mn;
      }
      float pr[16], rs = 0.f;
      #pragma unroll
      for (int r = 0; r < 16; r++) { pr[r] = __expf(S[r] - mrow); rs += pr[r]; }
      rs += __shfl_xor(rs, 32);
      lrow = lrow * fc + rs;
      // build PV B-frags (pack + half-swap + select), write to own P slot
      unsigned pA0 = pk2(pr[0], pr[1]),  pA1 = pk2(pr[2], pr[3]);
      unsigned pB0 = pk2(pr[4], pr[5]),  pB1 = pk2(pr[6], pr[7]);
      unsigned pC0 = pk2(pr[8], pr[9]),  pC1 = pk2(pr[10], pr[11]);
      unsigned pD0 = pk2(pr[12], pr[13]), pD1 = pk2(pr[14], pr[15]);
      unsigned sA0 = __shfl_xor(pA0, 32), sA1 = __shfl_xor(pA1, 32);
      unsigned sB0 = __shfl_xor(pB0, 32), sB1 = __shfl_xor(pB1, 32);
      unsigned sC0 = __shfl_xor(pC0, 32), sC1 = __shfl_xor(pC1, 32);
      unsigned sD0 = __shfl_xor(pD0, 32), sD1 = __shfl_xor(pD1, 32);
      u32x4 B0, B1;
      B0[0] = h ? sB0 : pA0;  B0[1] = h ? sB1 : pA1;
      B0[2] = h ? pB0 : sA0;  B0[3] = h ? pB1 : sA1;
      B1[0] = h ? sD0 : pC0;  B1[1] = h ? sD1 : pC1;
      B1[2] = h ? pD0 : sC0;  B1[3] = h ? pD1 : sC1;
      *(u32x4*)(Pq + lane * 16) = B0;
      *(u32x4*)(Pq + 1024 + lane * 16) = B1;
      if (need && h == 0) facl[qb * 32 + c] = fc;
      if (lane == 0) flg[qb] = need;
    }
    if (it + 1 < kNit)
      asm volatile("s_waitcnt lgkmcnt(0) vmcnt(4)" ::: "memory");  // K(it+1)+V(it) landed
    else
      asm volatile("s_waitcnt lgkmcnt(0) vmcnt(0)" ::: "memory");
    __builtin_amdgcn_s_barrier();                         // bar-alpha
  }

  // final PV of the last slab (V[kNit-1] in buffer (kNit-1)&1)
  pvstep((((kNit - 1) & 1) ? Vb1 : Vb0) + vbase);

  // ---------------- epilogue ----------------
  if (dh == 0) {
    const float iv = 1.0f / lrow;
    if (lane < 32) {
      m_part[ch * kB + q0 + qb * 32 + c] = mrow;
      l_part[ch * kB + q0 + qb * 32 + c] = lrow;
      facl[qb * 32 + c] = iv;
    }
  }
  asm volatile("s_waitcnt lgkmcnt(0)" ::: "memory");
  __builtin_amdgcn_s_barrier();
  const float iv0 = facl[(2 * qp) * 32 + c];
  const float iv1 = facl[(2 * qp + 1) * 32 + c];

  const size_t pvb = ((size_t)ch * kB + q0) * 512;
  #pragma unroll
  for (int ql = 0; ql < 2; ql++) {
    const int qrow = (2 * qp + ql) * 32 + c;
    const float iv = ql ? iv1 : iv0;
    #pragma unroll
    for (int cb = 0; cb < 4; cb++) {
      const int C = cq * 128 + cb * 32;
      #pragma unroll
      for (int a = 0; a < 4; a++) {
        unsigned lo = pk2(O[ql][cb][4 * a + 0] * iv, O[ql][cb][4 * a + 1] * iv);
        unsigned hi = pk2(O[ql][cb][4 * a + 2] * iv, O[ql][cb][4 * a + 3] * iv);
        u32x2 v = {lo, hi};
        *(u32x2*)(pvn + pvb + (size_t)qrow * 512 + C + 8 * a + 4 * h) = v;
      }
    }
  }
}

// ---------------------------------------------------------------------------
// Kernel 3: combine:  out = proj + alpha * (sum_c g_c l_c pvn_c) / (sum_c g_c l_c)
// ---------------------------------------------------------------------------
__global__ __launch_bounds__(256) void combine_kernel(
    const float* __restrict__ proj, const float* __restrict__ m_part,
    const float* __restrict__ l_part, const f16* __restrict__ pvn,
    const float* __restrict__ alpha_p, float* __restrict__ out)
{
  const int row = blockIdx.x;
  const int t = threadIdx.x;
  const float alpha = alpha_p[0];
  float M = -INFINITY;
  #pragma unroll
  for (int c = 0; c < kNch; c++) M = fmaxf(M, m_part[c * kB + row]);
  float gl[kNch];
  float T = 0.f;
  #pragma unroll
  for (int c = 0; c < kNch; c++) {
    gl[c] = __expf(m_part[c * kB + row] - M) * l_part[c * kB + row];
    T += gl[c];
  }
  const float s = alpha / T;
  #pragma unroll
  for (int half = 0; half < 2; half++) {
    const int col = t + half * 256;
    float acc = 0.f;
    #pragma unroll
    for (int c = 0; c < kNch; c++)
      acc += gl[c] * (float)pvn[((size_t)c * kB + row) * 512 + col];
    out[(size_t)row * 512 + col] = proj[(size_t)row * 512 + col] + acc * s;
  }
}

// ---------------------------------------------------------------------------
extern "C" void kernel_launch(void* const* d_in, const int* in_sizes, int n_in,
                              void* d_out, int out_size, void* d_ws, size_t ws_size,
                              hipStream_t stream) {
  (void)in_sizes; (void)n_in; (void)out_size; (void)ws_size;
  const float* x     = (const float*)d_in[0];
  const float* W     = (const float*)d_in[1];
  const float* bias  = (const float*)d_in[2];
  const float* cimg  = (const float*)d_in[3];
  const float* ctxt  = (const float*)d_in[4];
  const float* beta  = (const float*)d_in[5];
  const float* alpha = (const float*)d_in[6];
  float* out = (float*)d_out;
  char* ws = (char*)d_ws;

  float* proj = (float*)(ws + WS_PROJ);
  f16*   qhi  = (f16*)(ws + WS_QHI);
  float* mp   = (float*)(ws + WS_M);
  float* lp   = (float*)(ws + WS_L);
  f16*   pvn  = (f16*)(ws + WS_PV);
  f16*   K16  = (f16*)(ws + WS_K16);
  f16*   Vt16 = (f16*)(ws + WS_VT);

  hipFuncSetAttribute((const void*)attn_kernel,
                      hipFuncAttributeMaxDynamicSharedMemorySize, LDS_SZ);

  convk_kernel<<<(kKRows * 512 / 8 + 255) / 256, 256, 0, stream>>>(cimg, K16);
  transv_kernel<<<dim3(kVStride / 64, 8, kNch), 256, 0, stream>>>(ctxt, Vt16);
  gemm1_kernel<<<dim3(32, 8), 256, 0, stream>>>(x, W, bias, proj, qhi);
  attn_kernel<<<256, 512, LDS_SZ, stream>>>(K16, Vt16, qhi, beta, mp, lp, pvn);
  combine_kernel<<<2048, 256, 0, stream>>>(proj, mp, lp, pvn, alpha, out);
}